// Round 1
// baseline (16065.958 us; speedup 1.0000x reference)
//
#include <hip/hip_runtime.h>
#include <math.h>

#define NN 40000
#define EE 640000
#define FF 32
#define DD 64
#define GG 16
#define LL 3
#define TE 32

__device__ __forceinline__ float silu_f(float x){ return x / (1.f + __expf(-x)); }
__device__ __forceinline__ float sigmoid_f(float x){ return 1.f / (1.f + __expf(-x)); }

// ---------------- edge geometry ----------------
__global__ void k_geom(const float* __restrict__ pos, const int* __restrict__ edges,
                       float* __restrict__ dist, float* __restrict__ unit){
  int e = blockIdx.x*blockDim.x + threadIdx.x;
  if(e >= EE) return;
  int s = edges[2*e], d = edges[2*e+1];
  float dx = pos[3*d]-pos[3*s], dy = pos[3*d+1]-pos[3*s+1], dz = pos[3*d+2]-pos[3*s+2];
  float r = sqrtf(dx*dx+dy*dy+dz*dz + 1e-12f);
  dist[e] = r;
  float ir = 1.f/r;
  unit[3*e] = dx*ir; unit[3*e+1] = dy*ir; unit[3*e+2] = dz*ir;
}

// ---------------- per-graph node counts ----------------
__global__ void k_counts(const int* __restrict__ gids, int* __restrict__ cnt){
  int n = blockIdx.x*blockDim.x+threadIdx.x;
  if(n<NN) atomicAdd(&cnt[gids[n]], 1);
}

// ---------------- initial projection: s = silu(x@W1+b1)@W2+b2 ----------------
__global__ void k_proj(const float* __restrict__ x,
                       const float* __restrict__ W1, const float* __restrict__ b1,
                       const float* __restrict__ W2, const float* __restrict__ b2,
                       float* __restrict__ S){
  int n = blockIdx.x*blockDim.x+threadIdx.x;
  if(n>=NN) return;
  float xr[32];
  #pragma unroll
  for(int k=0;k<32;k++) xr[k] = x[n*32+k];
  float h[32];
  #pragma unroll 4
  for(int j=0;j<32;j++){
    float a = b1[j];
    #pragma unroll
    for(int k=0;k<32;k++) a += xr[k]*W1[k*32+j];
    h[j] = silu_f(a);
  }
  #pragma unroll 4
  for(int d=0; d<64; d++){
    float a = b2[d];
    #pragma unroll
    for(int j=0;j<32;j++) a += h[j]*W2[j*64+d];
    S[n*64+d] = a;
  }
}

// ---------------- graph-LN partial sums ----------------
__global__ void k_ln_reduce(const float* __restrict__ S, const int* __restrict__ gids,
                            float* __restrict__ GS, float* __restrict__ GQ){
  __shared__ float ls[GG], lq[GG];
  int t = threadIdx.x;
  if(t<GG){ ls[t]=0.f; lq[t]=0.f; }
  __syncthreads();
  int n = blockIdx.x*blockDim.x+t;
  if(n<NN){
    const float4* p = reinterpret_cast<const float4*>(S + (size_t)n*64);
    float sm=0.f, sq=0.f;
    #pragma unroll
    for(int i=0;i<16;i++){ float4 v=p[i];
      sm += v.x+v.y+v.z+v.w;
      sq += v.x*v.x+v.y*v.y+v.z*v.z+v.w*v.w; }
    int g = gids[n];
    atomicAdd(&ls[g], sm); atomicAdd(&lq[g], sq);
  }
  __syncthreads();
  if(t<GG){ atomicAdd(&GS[t], ls[t]); atomicAdd(&GQ[t], lq[t]); }
}

__global__ void k_ln_final(const float* __restrict__ GS, const float* __restrict__ GQ,
                           const int* __restrict__ cnt,
                           float* __restrict__ MEANV, float* __restrict__ INVV){
  int g = threadIdx.x;
  if(g<GG){
    float c = (float)cnt[g]*64.f;
    float m = GS[g]/c, e2 = GQ[g]/c;
    MEANV[g]=m; INVV[g]=rsqrtf(e2 - m*m + 1e-5f);
  }
}

// ---------------- node pre: sn, phi; SN doubles as s-accumulator ----------------
__global__ void k_node_pre(const float* __restrict__ S, const int* __restrict__ gids,
                           const float* __restrict__ MEANV, const float* __restrict__ INVV,
                           const float* __restrict__ lng, const float* __restrict__ lnb,
                           const float* __restrict__ W1, const float* __restrict__ b1,
                           const float* __restrict__ W2, const float* __restrict__ b2,
                           float* __restrict__ SN, float* __restrict__ PHI){
  int t = threadIdx.x, w = t>>6, lane = t&63;
  int n = blockIdx.x*4 + w;
  __shared__ float sh[4][65];
  __shared__ float hh[4][65];
  if(n < NN){
    int g = gids[n];
    float snv = (S[(size_t)n*64+lane] - MEANV[g]) * INVV[g] * lng[lane] + lnb[lane];
    SN[(size_t)n*64+lane] = snv;
    sh[w][lane] = snv;
  }
  __syncthreads();
  if(n < NN){
    float a = b1[lane];
    #pragma unroll 8
    for(int k=0;k<64;k++) a += sh[w][k]*W1[k*64+lane];
    hh[w][lane] = silu_f(a);
  }
  __syncthreads();
  if(n < NN){
    #pragma unroll
    for(int m=0;m<3;m++){
      int j = lane + 64*m;
      float a = b2[j];
      #pragma unroll 8
      for(int k=0;k<64;k++) a += hh[w][k]*W2[k*192+j];
      PHI[(size_t)n*192+j] = a;
    }
  }
}

// ---------------- fused edge kernel ----------------
__global__ __launch_bounds__(256) void k_edge(
    const float* __restrict__ S, const float* __restrict__ PHI,
    const float* __restrict__ V0, const float* __restrict__ DIST, const float* __restrict__ UNIT,
    const int* __restrict__ edges,
    const float* __restrict__ efW, const float* __restrict__ efb,
    const float* __restrict__ elW1, const float* __restrict__ elb1,
    const float* __restrict__ elW2, const float* __restrict__ elb2,
    const float* __restrict__ inW, const float* __restrict__ inb,
    const float* __restrict__ eiW, const float* __restrict__ eib,
    float* __restrict__ SN, float* __restrict__ V1)
{
  __shared__ float sCat[TE*193];   // cat(192), later Wphi(192)
  __shared__ float sH1[TE*129];
  __shared__ float sEs[TE*65];
  __shared__ int   sSrc[TE], sDst[TE];
  __shared__ float sDist[TE], sUnit[TE*3], sGate[TE];

  int t = threadIdx.x;
  int e0 = blockIdx.x * TE;
  if(t < TE){
    int e = e0 + t;
    sSrc[t] = edges[2*e]; sDst[t] = edges[2*e+1];
    sDist[t] = DIST[e];
  } else if(t < 2*TE){
    int i = t - TE; int e = e0 + i;
    sUnit[i*3+0]=UNIT[3*e]; sUnit[i*3+1]=UNIT[3*e+1]; sUnit[i*3+2]=UNIT[3*e+2];
  }
  __syncthreads();

  // P0: build cat = [s[src], s[dst], silu(dist*efW+efb)]
  for(int idx = t; idx < TE*192; idx += 256){
    int e = idx / 192, k = idx - e*192;
    float vcat;
    if(k < 64)        vcat = S[(size_t)sSrc[e]*64 + k];
    else if(k < 128)  vcat = S[(size_t)sDst[e]*64 + (k-64)];
    else { int j=k-128; vcat = silu_f(sDist[e]*efW[j] + efb[j]); }
    sCat[e*193+k] = vcat;
  }
  __syncthreads();

  // P1: h1 = silu(cat @ elW1 + b1)   (32 x 128)
  {
    int e = t >> 3, j0 = (t&7)*16;
    float acc[16];
    #pragma unroll
    for(int m=0;m<16;m++) acc[m] = elb1[j0+m];
    #pragma unroll 2
    for(int k=0;k<192;k++){
      float a = sCat[e*193+k];
      const float4* wr = reinterpret_cast<const float4*>(elW1 + k*128 + j0);
      #pragma unroll
      for(int q=0;q<4;q++){
        float4 wv = wr[q];
        acc[q*4+0] += a*wv.x; acc[q*4+1] += a*wv.y;
        acc[q*4+2] += a*wv.z; acc[q*4+3] += a*wv.w;
      }
    }
    #pragma unroll
    for(int m=0;m<16;m++) sH1[e*129 + j0 + m] = silu_f(acc[m]);
  }
  __syncthreads();

  // P2: es = h1 @ elW2 + b2   (32 x 64)
  {
    int e = t >> 3, j0 = (t&7)*8;
    float acc[8];
    #pragma unroll
    for(int m=0;m<8;m++) acc[m] = elb2[j0+m];
    #pragma unroll 2
    for(int k=0;k<128;k++){
      float a = sH1[e*129+k];
      const float4* wr = reinterpret_cast<const float4*>(elW2 + k*64 + j0);
      #pragma unroll
      for(int q=0;q<2;q++){
        float4 wv = wr[q];
        acc[q*4+0]+=a*wv.x; acc[q*4+1]+=a*wv.y; acc[q*4+2]+=a*wv.z; acc[q*4+3]+=a*wv.w;
      }
    }
    #pragma unroll
    for(int m=0;m<8;m++) sEs[e*65+j0+m] = acc[m];
  }
  __syncthreads();

  // P3: Wv = es @ inW + inb ; Wphi = Wv * phi[src]  -> sCat
  {
    int e = t >> 3, j0 = (t&7)*24;
    float acc[24];
    #pragma unroll
    for(int m=0;m<24;m++) acc[m] = inb[j0+m];
    #pragma unroll 2
    for(int k=0;k<64;k++){
      float a = sEs[e*65+k];
      const float4* wr = reinterpret_cast<const float4*>(inW + k*192 + j0);
      #pragma unroll
      for(int q=0;q<6;q++){
        float4 wv = wr[q];
        acc[q*4+0]+=a*wv.x; acc[q*4+1]+=a*wv.y; acc[q*4+2]+=a*wv.z; acc[q*4+3]+=a*wv.w;
      }
    }
    const float* phis = PHI + (size_t)sSrc[e]*192 + j0;
    #pragma unroll
    for(int m=0;m<24;m++) sCat[e*193 + j0 + m] = acc[m] * phis[m];
  }
  __syncthreads();

  // P4: gate = sigmoid(phi_s . eiW + eib)
  {
    int e = t >> 3, l8 = t & 7;
    float a = 0.f;
    #pragma unroll
    for(int i=0;i<8;i++){ int k = l8 + 8*i; a += sCat[e*193+k]*eiW[k]; }
    a += __shfl_xor(a, 1); a += __shfl_xor(a, 2); a += __shfl_xor(a, 4);
    if(l8==0) sGate[e] = sigmoid_f(a + eib[0]);
  }
  __syncthreads();

  // P5: ms / mv atomics
  for(int i=0;i<TE;i++){
    int e = i, r = t;
    float g = sGate[e];
    int dst = sDst[e];
    if(r < 64){
      float ms = sCat[e*193 + r] * g;
      atomicAdd(&SN[(size_t)dst*64 + r], ms);
    } else {
      int c = (r-64) >> 6, j = (r-64)&63;
      float vv = sCat[e*193 + 64 + j];
      float vs = sCat[e*193 + 128 + j];
      float mv = (V0[(size_t)sSrc[e]*192 + c*64 + j]*vv + vs*sUnit[e*3+c]) * g;
      atomicAdd(&V1[(size_t)dst*192 + c*64 + j], mv);
    }
  }
}

// ---------------- node post: UV update ----------------
__global__ void k_node_post(const float* __restrict__ SN, const float* __restrict__ V1,
                            const float* __restrict__ upUV,
                            const float* __restrict__ uvW1, const float* __restrict__ uvb1,
                            const float* __restrict__ uvW2, const float* __restrict__ uvb2,
                            float* __restrict__ Sout, float* __restrict__ V0)
{
  int t = threadIdx.x, w = t>>6, j = t&63;
  int n = blockIdx.x*4 + w;
  __shared__ float vsh[4][3][64];
  __shared__ float cat2[4][129];
  __shared__ float hh[4][65];
  if(n < NN){
    #pragma unroll
    for(int c=0;c<3;c++) vsh[w][c][j] = V1[(size_t)n*192 + c*64 + j];
  }
  __syncthreads();
  float Uv[3]={0,0,0}, Vv[3]={0,0,0};
  float s_new = 0.f;
  if(n < NN){
    #pragma unroll 4
    for(int k=0;k<64;k++){
      float wu = upUV[k*128 + j];
      float wv = upUV[k*128 + 64 + j];
      #pragma unroll
      for(int c=0;c<3;c++){ float vk = vsh[w][c][k]; Uv[c] += vk*wu; Vv[c] += vk*wv; }
    }
    s_new = SN[(size_t)n*64 + j];
    float vn2 = Vv[0]*Vv[0]+Vv[1]*Vv[1]+Vv[2]*Vv[2];
    cat2[w][j] = sqrtf(vn2 + 1e-6f);
    cat2[w][64+j] = s_new;
  }
  __syncthreads();
  if(n<NN){
    float a = uvb1[j];
    #pragma unroll 8
    for(int k=0;k<128;k++) a += cat2[w][k]*uvW1[k*64+j];
    hh[w][j] = silu_f(a);
  }
  __syncthreads();
  if(n<NN){
    float a0=uvb2[j], a1=uvb2[64+j], a2=uvb2[128+j];
    #pragma unroll 4
    for(int k=0;k<64;k++){
      float h = hh[w][k];
      a0 += h*uvW2[k*192+j]; a1 += h*uvW2[k*192+64+j]; a2 += h*uvW2[k*192+128+j];
    }
    float inner = Uv[0]*Vv[0]+Uv[1]*Vv[1]+Uv[2]*Vv[2];
    Sout[(size_t)n*64+j] = s_new + a2 + a1*inner;
    #pragma unroll
    for(int c=0;c<3;c++) V0[(size_t)n*192 + c*64 + j] = vsh[w][c][j] + a0*Uv[c];
  }
}

extern "C" void kernel_launch(void* const* d_in, const int* in_sizes, int n_in,
                              void* d_out, int out_size, void* d_ws, size_t ws_size,
                              hipStream_t stream)
{
  const float* node_features  = (const float*)d_in[0];
  const float* node_positions = (const float*)d_in[1];
  const int*   edges          = (const int*)  d_in[2];
  const int*   gids           = (const int*)  d_in[3];
  const float* proj_W1 = (const float*)d_in[4];
  const float* proj_b1 = (const float*)d_in[5];
  const float* proj_W2 = (const float*)d_in[6];
  const float* proj_b2 = (const float*)d_in[7];
  const float* ef_W  = (const float*)d_in[8];
  const float* ef_b  = (const float*)d_in[9];
  const float* el_W1 = (const float*)d_in[10];
  const float* el_b1 = (const float*)d_in[11];
  const float* el_W2 = (const float*)d_in[12];
  const float* el_b2 = (const float*)d_in[13];
  const float* in_W  = (const float*)d_in[14];
  const float* in_b  = (const float*)d_in[15];
  const float* msg_W1= (const float*)d_in[16];
  const float* msg_b1= (const float*)d_in[17];
  const float* msg_W2= (const float*)d_in[18];
  const float* msg_b2= (const float*)d_in[19];
  const float* ei_W  = (const float*)d_in[20];
  const float* ei_b  = (const float*)d_in[21];
  const float* ln_g  = (const float*)d_in[22];
  const float* ln_b  = (const float*)d_in[23];
  const float* up_UV = (const float*)d_in[24];
  const float* uv_W1 = (const float*)d_in[25];
  const float* uv_b1 = (const float*)d_in[26];
  const float* uv_W2 = (const float*)d_in[27];
  const float* uv_b2 = (const float*)d_in[28];

  float* ws = (float*)d_ws;
  size_t off = 0;
  float* S    = ws + off; off += (size_t)NN*64;
  float* SN   = ws + off; off += (size_t)NN*64;
  float* PHI  = ws + off; off += (size_t)NN*192;
  float* V0   = ws + off; off += (size_t)NN*192;
  float* V1   = ws + off; off += (size_t)NN*192;
  float* DIST = ws + off; off += EE;
  float* UNIT = ws + off; off += (size_t)EE*3;
  float* GS   = ws + off; off += GG;
  float* GQ   = ws + off; off += GG;
  float* MEANV= ws + off; off += GG;
  float* INVV = ws + off; off += GG;
  int*   CNT  = (int*)(ws + off); off += GG;

  hipMemsetAsync(CNT, 0, GG*sizeof(int), stream);
  hipMemsetAsync(V0, 0, (size_t)NN*192*sizeof(float), stream);

  k_geom  <<<(EE+255)/256, 256, 0, stream>>>(node_positions, edges, DIST, UNIT);
  k_counts<<<(NN+255)/256, 256, 0, stream>>>(gids, CNT);
  k_proj  <<<(NN+255)/256, 256, 0, stream>>>(node_features, proj_W1, proj_b1, proj_W2, proj_b2, S);

  for(int l=0; l<LL; l++){
    hipMemsetAsync(GS, 0, 2*GG*sizeof(float), stream);   // GS and GQ are contiguous
    k_ln_reduce<<<(NN+255)/256, 256, 0, stream>>>(S, gids, GS, GQ);
    k_ln_final <<<1, 64, 0, stream>>>(GS, GQ, CNT, MEANV, INVV);
    k_node_pre <<<(NN+3)/4, 256, 0, stream>>>(S, gids, MEANV, INVV,
                   ln_g + l*64, ln_b + l*64,
                   msg_W1 + l*64*64, msg_b1 + l*64,
                   msg_W2 + l*64*192, msg_b2 + l*192, SN, PHI);
    hipMemcpyAsync(V1, V0, (size_t)NN*192*sizeof(float), hipMemcpyDeviceToDevice, stream);
    k_edge<<<EE/TE, 256, 0, stream>>>(S, PHI, V0, DIST, UNIT, edges,
                   ef_W + l*64, ef_b + l*64,
                   el_W1 + l*192*128, el_b1 + l*128,
                   el_W2 + l*128*64, el_b2 + l*64,
                   in_W + l*64*192, in_b + l*192,
                   ei_W + l*64, ei_b + l, SN, V1);
    float* sout = (l == LL-1) ? (float*)d_out : S;
    k_node_post<<<(NN+3)/4, 256, 0, stream>>>(SN, V1,
                   up_UV + l*64*128,
                   uv_W1 + l*128*64, uv_b1 + l*64,
                   uv_W2 + l*64*192, uv_b2 + l*192, sout, V0);
  }
}

// Round 3
// 5278.131 us; speedup vs baseline: 3.0439x; 3.0439x over previous
//
#include <hip/hip_runtime.h>
#include <hip/hip_bf16.h>
#include <math.h>

#define NN 40000
#define EE 640000
#define GG 16
#define LL 3
#define TE 64

// LDS strides (ushort units). All chosen 16B-aligned, 2-way-max bank aliasing.
#define STC 200   // K=192 rows (cat / W1t)
#define STH 136   // K=128 rows (h1 / W2t)
#define STE 72    // K=64 rows (es / W3t)
#define PCAT 12800  // 64*STC  plane pitch, cat
#define PW   12800  // weight buffer plane pitch
#define PH1  8704   // 64*STH
#define PES  4608   // 64*STE

typedef __attribute__((ext_vector_type(8))) short s8v;   // 8 bf16
typedef __attribute__((ext_vector_type(4))) float f4v;   // MFMA acc

__device__ __forceinline__ float silu_f(float x){ return x / (1.f + __expf(-x)); }
__device__ __forceinline__ float sigmoid_f(float x){ return 1.f / (1.f + __expf(-x)); }
__device__ __forceinline__ ushort f2b(float x){
  __hip_bfloat16 h = __float2bfloat16(x);
  return __builtin_bit_cast(ushort, h);
}
__device__ __forceinline__ float b2f(ushort u){
  __hip_bfloat16 h = __builtin_bit_cast(__hip_bfloat16, u);
  return __bfloat162float(h);
}

// ---------------- edge geometry: UD[e] = {ux,uy,uz,dist} ----------------
__global__ void k_geom(const float* __restrict__ pos, const int* __restrict__ edges,
                       float4* __restrict__ UD){
  int e = blockIdx.x*blockDim.x + threadIdx.x;
  if(e >= EE) return;
  int s = edges[2*e], d = edges[2*e+1];
  float dx = pos[3*d]-pos[3*s], dy = pos[3*d+1]-pos[3*s+1], dz = pos[3*d+2]-pos[3*s+2];
  float r = sqrtf(dx*dx+dy*dy+dz*dz + 1e-12f);
  float ir = 1.f/r;
  UD[e] = make_float4(dx*ir, dy*ir, dz*ir, r);
}

// ---------------- per-graph node counts ----------------
__global__ void k_counts(const int* __restrict__ gids, int* __restrict__ cnt){
  int n = blockIdx.x*blockDim.x+threadIdx.x;
  if(n<NN) atomicAdd(&cnt[gids[n]], 1);
}

// ---------------- weight prep: transposed hi/lo bf16 planes ----------------
__global__ void k_prep_w(const float* __restrict__ elW1, const float* __restrict__ elW2,
                         const float* __restrict__ inW,
                         ushort* __restrict__ W1H, ushort* __restrict__ W1L,
                         ushort* __restrict__ W2H, ushort* __restrict__ W2L,
                         ushort* __restrict__ W3H, ushort* __restrict__ W3L){
  int tid = blockIdx.x*256 + threadIdx.x;
  const int per = 24576 + 8192 + 12288;
  if(tid >= LL*per) return;
  int l = tid/per, r = tid - l*per;
  float w; ushort* dh; ushort* dl; int idx;
  if(r < 24576){                 // W1t[n][k] = el_W1[k][n], 128x192
    int n = r/192, k = r - n*192;
    w = elW1[l*24576 + k*128 + n];
    dh = W1H; dl = W1L; idx = l*24576 + r;
  } else if(r < 32768){          // W2t[n][k] = el_W2[k][n], 64x128
    int i = r - 24576; int n = i/128, k = i - n*128;
    w = elW2[l*8192 + k*64 + n];
    dh = W2H; dl = W2L; idx = l*8192 + i;
  } else {                       // W3t[n][k] = in_W[k][n], 192x64
    int i = r - 32768; int n = i/64, k = i - n*64;
    w = inW[l*12288 + k*192 + n];
    dh = W3H; dl = W3L; idx = l*12288 + i;
  }
  ushort hi = f2b(w);
  dh[idx] = hi;
  dl[idx] = f2b(w - b2f(hi));
}

// ---------------- initial projection ----------------
__global__ void k_proj(const float* __restrict__ x,
                       const float* __restrict__ W1, const float* __restrict__ b1,
                       const float* __restrict__ W2, const float* __restrict__ b2,
                       float* __restrict__ S){
  int n = blockIdx.x*blockDim.x+threadIdx.x;
  if(n>=NN) return;
  float xr[32];
  #pragma unroll
  for(int k=0;k<32;k++) xr[k] = x[n*32+k];
  float h[32];
  #pragma unroll 4
  for(int j=0;j<32;j++){
    float a = b1[j];
    #pragma unroll
    for(int k=0;k<32;k++) a += xr[k]*W1[k*32+j];
    h[j] = silu_f(a);
  }
  #pragma unroll 4
  for(int d=0; d<64; d++){
    float a = b2[d];
    #pragma unroll
    for(int j=0;j<32;j++) a += h[j]*W2[j*64+d];
    S[n*64+d] = a;
  }
}

// ---------------- graph-LN partial sums ----------------
__global__ void k_ln_reduce(const float* __restrict__ S, const int* __restrict__ gids,
                            float* __restrict__ GS, float* __restrict__ GQ){
  __shared__ float ls[GG], lq[GG];
  int t = threadIdx.x;
  if(t<GG){ ls[t]=0.f; lq[t]=0.f; }
  __syncthreads();
  int n = blockIdx.x*blockDim.x+t;
  if(n<NN){
    const float4* p = reinterpret_cast<const float4*>(S + (size_t)n*64);
    float sm=0.f, sq=0.f;
    #pragma unroll
    for(int i=0;i<16;i++){ float4 v=p[i];
      sm += v.x+v.y+v.z+v.w;
      sq += v.x*v.x+v.y*v.y+v.z*v.z+v.w*v.w; }
    int g = gids[n];
    atomicAdd(&ls[g], sm); atomicAdd(&lq[g], sq);
  }
  __syncthreads();
  if(t<GG){ atomicAdd(&GS[t], ls[t]); atomicAdd(&GQ[t], lq[t]); }
}

__global__ void k_ln_final(const float* __restrict__ GS, const float* __restrict__ GQ,
                           const int* __restrict__ cnt,
                           float* __restrict__ MEANV, float* __restrict__ INVV){
  int g = threadIdx.x;
  if(g<GG){
    float c = (float)cnt[g]*64.f;
    float m = GS[g]/c, e2 = GQ[g]/c;
    MEANV[g]=m; INVV[g]=rsqrtf(e2 - m*m + 1e-5f);
  }
}

// ---------------- node pre: sn -> SN, phi (fp32) ----------------
__global__ void k_node_pre(const float* __restrict__ S, const int* __restrict__ gids,
                           const float* __restrict__ MEANV, const float* __restrict__ INVV,
                           const float* __restrict__ lng, const float* __restrict__ lnb,
                           const float* __restrict__ W1, const float* __restrict__ b1,
                           const float* __restrict__ W2, const float* __restrict__ b2,
                           float* __restrict__ SN, float* __restrict__ PHI){
  int t = threadIdx.x, w = t>>6, lane = t&63;
  int n = blockIdx.x*4 + w;
  __shared__ float sh[4][65];
  __shared__ float hh[4][65];
  if(n < NN){
    int g = gids[n];
    float snv = (S[(size_t)n*64+lane] - MEANV[g]) * INVV[g] * lng[lane] + lnb[lane];
    SN[(size_t)n*64+lane] = snv;
    sh[w][lane] = snv;
  }
  __syncthreads();
  if(n < NN){
    float a = b1[lane];
    #pragma unroll 8
    for(int k=0;k<64;k++) a += sh[w][k]*W1[k*64+lane];
    hh[w][lane] = silu_f(a);
  }
  __syncthreads();
  if(n < NN){
    #pragma unroll
    for(int m=0;m<3;m++){
      int j = lane + 64*m;
      float a = b2[j];
      #pragma unroll 8
      for(int k=0;k<64;k++) a += hh[w][k]*W2[k*192+j];
      PHI[(size_t)n*192+j] = a;
    }
  }
}

// ---------------- fused split-precision MFMA edge kernel ----------------
__device__ __forceinline__ void stage_w(ushort* dst, const ushort* gh, const ushort* gl,
                                        int rows, int cpr, int stride, int t){
  int total = rows*cpr;
  for(int c = t; c < total; c += 256){
    int row = c / cpr, col = (c - row*cpr)*8;
    *reinterpret_cast<s8v*>(&dst[row*stride + col]) =
        *reinterpret_cast<const s8v*>(&gh[row*cpr*8 + col]);
    *reinterpret_cast<s8v*>(&dst[PW + row*stride + col]) =
        *reinterpret_cast<const s8v*>(&gl[row*cpr*8 + col]);
  }
}

__global__ __launch_bounds__(256,1) void k_edge(
    const float* __restrict__ S, const float* __restrict__ PHI,
    const float* __restrict__ V0, const float4* __restrict__ UD,
    const int* __restrict__ edges,
    const float* __restrict__ efW, const float* __restrict__ efb,
    const ushort* __restrict__ GW1H, const ushort* __restrict__ GW1L, const float* __restrict__ elb1,
    const ushort* __restrict__ GW2H, const ushort* __restrict__ GW2L, const float* __restrict__ elb2,
    const ushort* __restrict__ GW3H, const ushort* __restrict__ GW3L, const float* __restrict__ inb,
    const float* __restrict__ eiW, const float* __restrict__ eib,
    float* __restrict__ SN, float* __restrict__ V1)
{
  __shared__ __align__(16) ushort sCat[2*PCAT];
  __shared__ __align__(16) ushort sW  [2*PW];
  __shared__ __align__(16) ushort sH1 [2*PH1];
  __shared__ __align__(16) ushort sEs [2*PES];
  __shared__ int   sSrc[TE], sDst[TE];
  __shared__ float sUnit[TE*3];

  const int t  = threadIdx.x;
  const int e0 = blockIdx.x * TE;

  // ---- stage edge meta
  if(t < TE){
    int e = e0 + t;
    sSrc[t] = edges[2*e]; sDst[t] = edges[2*e+1];
    float4 ud = UD[e];
    sUnit[3*t] = ud.x; sUnit[3*t+1] = ud.y; sUnit[3*t+2] = ud.z;
  }
  // ---- build cat tile hi/lo: [s[src] | s[dst] | silu(dist*efW+efb)]
  {
    int p = t >> 6, e = t & 63;
    int eg = e0 + e;
    if(p < 2){
      int node = edges[2*eg + p];
      const float4* sp = reinterpret_cast<const float4*>(S + (size_t)node*64);
      int base = e*STC + 64*p;
      #pragma unroll
      for(int q=0;q<16;q++){
        float4 v = sp[q];
        ushort4 bh, bl;
        bh.x=f2b(v.x); bl.x=f2b(v.x-b2f(bh.x));
        bh.y=f2b(v.y); bl.y=f2b(v.y-b2f(bh.y));
        bh.z=f2b(v.z); bl.z=f2b(v.z-b2f(bh.z));
        bh.w=f2b(v.w); bl.w=f2b(v.w-b2f(bh.w));
        *reinterpret_cast<ushort4*>(&sCat[base + 4*q]) = bh;
        *reinterpret_cast<ushort4*>(&sCat[PCAT + base + 4*q]) = bl;
      }
    } else {
      float dist = UD[eg].w;
      int j0 = (p==2) ? 0 : 32;
      #pragma unroll
      for(int j=0;j<32;j++){
        int jj = j0 + j;
        float v = silu_f(dist*efW[jj] + efb[jj]);
        ushort hi = f2b(v);
        sCat[e*STC + 128 + jj] = hi;
        sCat[PCAT + e*STC + 128 + jj] = f2b(v - b2f(hi));
      }
    }
  }
  // ---- stage W1 half 0
  stage_w(sW, GW1H, GW1L, 64, 24, STC, t);
  __syncthreads();

  const int w  = t >> 6, l = t & 63;
  const int row0 = w*16;
  const int lr = l & 15, lg = l >> 4;

  // ---- A fragments of cat (held through GEMM1)
  s8v ah[6], al[6];
  #pragma unroll
  for(int k=0;k<6;k++){
    int ro = (row0+lr)*STC + k*32 + lg*8;
    ah[k] = *reinterpret_cast<const s8v*>(&sCat[ro]);
    al[k] = *reinterpret_cast<const s8v*>(&sCat[PCAT + ro]);
  }

  // ---- GEMM1: h1 = silu(cat @ W1 + b1), in two 64-col halves
  for(int h=0; h<2; h++){
    if(h == 1){
      __syncthreads();                       // all waves done with half-0 weights
      stage_w(sW, GW1H + 64*192, GW1L + 64*192, 64, 24, STC, t);
      __syncthreads();
    }
    f4v acc[4];
    #pragma unroll
    for(int jl=0;jl<4;jl++){
      float bv = elb1[64*h + 16*jl + lr];
      acc[jl] = (f4v){bv,bv,bv,bv};
    }
    #pragma unroll
    for(int k=0;k<6;k++){
      s8v bh[4], bl[4];
      #pragma unroll
      for(int jl=0;jl<4;jl++){
        int ro = (16*jl+lr)*STC + k*32 + lg*8;
        bh[jl] = *reinterpret_cast<const s8v*>(&sW[ro]);
        bl[jl] = *reinterpret_cast<const s8v*>(&sW[PW + ro]);
      }
      #pragma unroll
      for(int jl=0;jl<4;jl++) acc[jl] = __builtin_amdgcn_mfma_f32_16x16x32_bf16(ah[k], bh[jl], acc[jl], 0,0,0);
      #pragma unroll
      for(int jl=0;jl<4;jl++) acc[jl] = __builtin_amdgcn_mfma_f32_16x16x32_bf16(al[k], bh[jl], acc[jl], 0,0,0);
      #pragma unroll
      for(int jl=0;jl<4;jl++) acc[jl] = __builtin_amdgcn_mfma_f32_16x16x32_bf16(ah[k], bl[jl], acc[jl], 0,0,0);
    }
    #pragma unroll
    for(int jl=0;jl<4;jl++){
      #pragma unroll
      for(int r=0;r<4;r++){
        float v = silu_f(acc[jl][r]);
        ushort hi = f2b(v);
        int o = (row0 + lg*4 + r)*STH + 64*h + 16*jl + lr;
        sH1[o] = hi;
        sH1[PH1 + o] = f2b(v - b2f(hi));
      }
    }
  }
  __syncthreads();
  // ---- stage W2t
  stage_w(sW, GW2H, GW2L, 64, 16, STH, t);
  __syncthreads();

  // ---- GEMM2: es = h1 @ W2 + b2
  {
    s8v a2h[4], a2l[4];
    #pragma unroll
    for(int k=0;k<4;k++){
      int ro = (row0+lr)*STH + k*32 + lg*8;
      a2h[k] = *reinterpret_cast<const s8v*>(&sH1[ro]);
      a2l[k] = *reinterpret_cast<const s8v*>(&sH1[PH1 + ro]);
    }
    f4v acc[4];
    #pragma unroll
    for(int jl=0;jl<4;jl++){
      float bv = elb2[16*jl + lr];
      acc[jl] = (f4v){bv,bv,bv,bv};
    }
    #pragma unroll
    for(int k=0;k<4;k++){
      s8v bh[4], bl[4];
      #pragma unroll
      for(int jl=0;jl<4;jl++){
        int ro = (16*jl+lr)*STH + k*32 + lg*8;
        bh[jl] = *reinterpret_cast<const s8v*>(&sW[ro]);
        bl[jl] = *reinterpret_cast<const s8v*>(&sW[PW + ro]);
      }
      #pragma unroll
      for(int jl=0;jl<4;jl++) acc[jl] = __builtin_amdgcn_mfma_f32_16x16x32_bf16(a2h[k], bh[jl], acc[jl], 0,0,0);
      #pragma unroll
      for(int jl=0;jl<4;jl++) acc[jl] = __builtin_amdgcn_mfma_f32_16x16x32_bf16(a2l[k], bh[jl], acc[jl], 0,0,0);
      #pragma unroll
      for(int jl=0;jl<4;jl++) acc[jl] = __builtin_amdgcn_mfma_f32_16x16x32_bf16(a2h[k], bl[jl], acc[jl], 0,0,0);
    }
    #pragma unroll
    for(int jl=0;jl<4;jl++){
      #pragma unroll
      for(int r=0;r<4;r++){
        float v = acc[jl][r];
        ushort hi = f2b(v);
        int o = (row0 + lg*4 + r)*STE + 16*jl + lr;
        sEs[o] = hi;
        sEs[PES + o] = f2b(v - b2f(hi));
      }
    }
  }

  // ---- GEMM3: Wv = es @ inW + inb, in three 64-col chunks; fused epilogue
  {
    s8v a3h[2], a3l[2];
    #pragma unroll
    for(int k=0;k<2;k++){
      int ro = (row0+lr)*STE + k*32 + lg*8;
      a3h[k] = *reinterpret_cast<const s8v*>(&sEs[ro]);
      a3l[k] = *reinterpret_cast<const s8v*>(&sEs[PES + ro]);
    }
    int er[4], sr[4], dr[4];
    #pragma unroll
    for(int r=0;r<4;r++){
      int el = row0 + lg*4 + r;
      er[r] = el; sr[r] = sSrc[el]; dr[r] = sDst[el];
    }
    f4v acc3[12];
    float gp[4] = {0.f,0.f,0.f,0.f};

    for(int c=0; c<3; c++){
      __syncthreads();                       // protect sW before restage
      stage_w(sW, GW3H + 64*c*64, GW3L + 64*c*64, 64, 8, STE, t);
      __syncthreads();
      // prefetch phi for this chunk
      float ph[16];
      #pragma unroll
      for(int jl=0;jl<4;jl++)
        #pragma unroll
        for(int r=0;r<4;r++)
          ph[jl*4+r] = PHI[(size_t)sr[r]*192 + 64*c + 16*jl + lr];
      #pragma unroll
      for(int jl=0;jl<4;jl++){
        int n = 64*c + 16*jl + lr;
        float bv = inb[n];
        f4v acc = (f4v){bv,bv,bv,bv};
        #pragma unroll
        for(int k=0;k<2;k++){
          int ro = (16*jl+lr)*STE + k*32 + lg*8;
          s8v bh = *reinterpret_cast<const s8v*>(&sW[ro]);
          s8v bl = *reinterpret_cast<const s8v*>(&sW[PW + ro]);
          acc = __builtin_amdgcn_mfma_f32_16x16x32_bf16(a3h[k], bh, acc, 0,0,0);
          acc = __builtin_amdgcn_mfma_f32_16x16x32_bf16(a3l[k], bh, acc, 0,0,0);
          acc = __builtin_amdgcn_mfma_f32_16x16x32_bf16(a3h[k], bl, acc, 0,0,0);
        }
        #pragma unroll
        for(int r=0;r<4;r++) acc[r] *= ph[jl*4+r];
        if(c == 0){
          float wn = eiW[16*jl + lr];
          #pragma unroll
          for(int r=0;r<4;r++) gp[r] += acc[r]*wn;
        }
        acc3[c*4+jl] = acc;
      }
    }
    // gate reduce across the 16 lanes of each row-group
    #pragma unroll
    for(int off=1; off<16; off<<=1){
      #pragma unroll
      for(int r=0;r<4;r++) gp[r] += __shfl_xor(gp[r], off);
    }
    float gt[4];
    #pragma unroll
    for(int r=0;r<4;r++) gt[r] = sigmoid_f(gp[r] + eib[0]);
    // ms atomics
    #pragma unroll
    for(int j=0;j<4;j++){
      #pragma unroll
      for(int r=0;r<4;r++)
        atomicAdd(&SN[(size_t)dr[r]*64 + 16*j + lr], acc3[j][r]*gt[r]);
    }
    // mv atomics
    float un[4][3];
    #pragma unroll
    for(int r=0;r<4;r++){
      #pragma unroll
      for(int c=0;c<3;c++) un[r][c] = sUnit[er[r]*3 + c];
    }
    #pragma unroll
    for(int c=0;c<3;c++){
      #pragma unroll
      for(int jt=0;jt<4;jt++){
        int jcol = 16*jt + lr;
        #pragma unroll
        for(int r=0;r<4;r++){
          float vv = acc3[4+jt][r];
          float vs = acc3[8+jt][r];
          float v0 = V0[(size_t)sr[r]*192 + c*64 + jcol];
          atomicAdd(&V1[(size_t)dr[r]*192 + c*64 + jcol], (v0*vv + vs*un[r][c])*gt[r]);
        }
      }
    }
  }
}

// ---------------- node post: UV update ----------------
__global__ void k_node_post(const float* __restrict__ SN, const float* __restrict__ V1,
                            const float* __restrict__ upUV,
                            const float* __restrict__ uvW1, const float* __restrict__ uvb1,
                            const float* __restrict__ uvW2, const float* __restrict__ uvb2,
                            float* __restrict__ Sout, float* __restrict__ V0)
{
  int t = threadIdx.x, w = t>>6, j = t&63;
  int n = blockIdx.x*4 + w;
  __shared__ float vsh[4][3][64];
  __shared__ float cat2[4][129];
  __shared__ float hh[4][65];
  if(n < NN){
    #pragma unroll
    for(int c=0;c<3;c++) vsh[w][c][j] = V1[(size_t)n*192 + c*64 + j];
  }
  __syncthreads();
  float Uv[3]={0,0,0}, Vv[3]={0,0,0};
  float s_new = 0.f;
  if(n < NN){
    #pragma unroll 4
    for(int k=0;k<64;k++){
      float wu = upUV[k*128 + j];
      float wv = upUV[k*128 + 64 + j];
      #pragma unroll
      for(int c=0;c<3;c++){ float vk = vsh[w][c][k]; Uv[c] += vk*wu; Vv[c] += vk*wv; }
    }
    s_new = SN[(size_t)n*64 + j];
    float vn2 = Vv[0]*Vv[0]+Vv[1]*Vv[1]+Vv[2]*Vv[2];
    cat2[w][j] = sqrtf(vn2 + 1e-6f);
    cat2[w][64+j] = s_new;
  }
  __syncthreads();
  if(n<NN){
    float a = uvb1[j];
    #pragma unroll 8
    for(int k=0;k<128;k++) a += cat2[w][k]*uvW1[k*64+j];
    hh[w][j] = silu_f(a);
  }
  __syncthreads();
  if(n<NN){
    float a0=uvb2[j], a1=uvb2[64+j], a2=uvb2[128+j];
    #pragma unroll 4
    for(int k=0;k<64;k++){
      float h = hh[w][k];
      a0 += h*uvW2[k*192+j]; a1 += h*uvW2[k*192+64+j]; a2 += h*uvW2[k*192+128+j];
    }
    float inner = Uv[0]*Vv[0]+Uv[1]*Vv[1]+Uv[2]*Vv[2];
    Sout[(size_t)n*64+j] = s_new + a2 + a1*inner;
    #pragma unroll
    for(int c=0;c<3;c++) V0[(size_t)n*192 + c*64 + j] = vsh[w][c][j] + a0*Uv[c];
  }
}

extern "C" void kernel_launch(void* const* d_in, const int* in_sizes, int n_in,
                              void* d_out, int out_size, void* d_ws, size_t ws_size,
                              hipStream_t stream)
{
  const float* node_features  = (const float*)d_in[0];
  const float* node_positions = (const float*)d_in[1];
  const int*   edges          = (const int*)  d_in[2];
  const int*   gids           = (const int*)  d_in[3];
  const float* proj_W1 = (const float*)d_in[4];
  const float* proj_b1 = (const float*)d_in[5];
  const float* proj_W2 = (const float*)d_in[6];
  const float* proj_b2 = (const float*)d_in[7];
  const float* ef_W  = (const float*)d_in[8];
  const float* ef_b  = (const float*)d_in[9];
  const float* el_W1 = (const float*)d_in[10];
  const float* el_b1 = (const float*)d_in[11];
  const float* el_W2 = (const float*)d_in[12];
  const float* el_b2 = (const float*)d_in[13];
  const float* in_W  = (const float*)d_in[14];
  const float* in_b  = (const float*)d_in[15];
  const float* msg_W1= (const float*)d_in[16];
  const float* msg_b1= (const float*)d_in[17];
  const float* msg_W2= (const float*)d_in[18];
  const float* msg_b2= (const float*)d_in[19];
  const float* ei_W  = (const float*)d_in[20];
  const float* ei_b  = (const float*)d_in[21];
  const float* ln_g  = (const float*)d_in[22];
  const float* ln_b  = (const float*)d_in[23];
  const float* up_UV = (const float*)d_in[24];
  const float* uv_W1 = (const float*)d_in[25];
  const float* uv_b1 = (const float*)d_in[26];
  const float* uv_W2 = (const float*)d_in[27];
  const float* uv_b2 = (const float*)d_in[28];

  float* ws = (float*)d_ws;
  size_t off = 0;
  float*  S    = ws + off; off += (size_t)NN*64;
  float*  SN   = ws + off; off += (size_t)NN*64;
  float*  PHI  = ws + off; off += (size_t)NN*192;
  float*  V0   = ws + off; off += (size_t)NN*192;
  float*  V1   = ws + off; off += (size_t)NN*192;
  float4* UD   = (float4*)(ws + off); off += (size_t)EE*4;
  float*  GS   = ws + off; off += GG;
  float*  GQ   = ws + off; off += GG;
  float*  MEANV= ws + off; off += GG;
  float*  INVV = ws + off; off += GG;
  int*    CNT  = (int*)(ws + off); off += GG;
  off = (off + 3) & ~(size_t)3;          // 16B-align weight planes
  ushort* W1H = (ushort*)(ws + off); off += (size_t)LL*24576/2;
  ushort* W1L = (ushort*)(ws + off); off += (size_t)LL*24576/2;
  ushort* W2H = (ushort*)(ws + off); off += (size_t)LL*8192/2;
  ushort* W2L = (ushort*)(ws + off); off += (size_t)LL*8192/2;
  ushort* W3H = (ushort*)(ws + off); off += (size_t)LL*12288/2;
  ushort* W3L = (ushort*)(ws + off); off += (size_t)LL*12288/2;

  hipMemsetAsync(CNT, 0, GG*sizeof(int), stream);
  hipMemsetAsync(V0, 0, (size_t)NN*192*sizeof(float), stream);

  k_geom  <<<(EE+255)/256, 256, 0, stream>>>(node_positions, edges, UD);
  k_counts<<<(NN+255)/256, 256, 0, stream>>>(gids, CNT);
  k_proj  <<<(NN+255)/256, 256, 0, stream>>>(node_features, proj_W1, proj_b1, proj_W2, proj_b2, S);
  k_prep_w<<<(LL*45056+255)/256, 256, 0, stream>>>(el_W1, el_W2, in_W, W1H, W1L, W2H, W2L, W3H, W3L);

  for(int l=0; l<LL; l++){
    hipMemsetAsync(GS, 0, 2*GG*sizeof(float), stream);
    k_ln_reduce<<<(NN+255)/256, 256, 0, stream>>>(S, gids, GS, GQ);
    k_ln_final <<<1, 64, 0, stream>>>(GS, GQ, CNT, MEANV, INVV);
    k_node_pre <<<(NN+3)/4, 256, 0, stream>>>(S, gids, MEANV, INVV,
                   ln_g + l*64, ln_b + l*64,
                   msg_W1 + l*64*64, msg_b1 + l*64,
                   msg_W2 + l*64*192, msg_b2 + l*192, SN, PHI);
    hipMemcpyAsync(V1, V0, (size_t)NN*192*sizeof(float), hipMemcpyDeviceToDevice, stream);
    k_edge<<<EE/TE, 256, 0, stream>>>(S, PHI, V0, UD, edges,
                   ef_W + l*64, ef_b + l*64,
                   W1H + l*24576, W1L + l*24576, el_b1 + l*128,
                   W2H + l*8192,  W2L + l*8192,  el_b2 + l*64,
                   W3H + l*12288, W3L + l*12288, in_b + l*192,
                   ei_W + l*64, ei_b + l, SN, V1);
    float* sout = (l == LL-1) ? (float*)d_out : S;
    k_node_post<<<(NN+3)/4, 256, 0, stream>>>(SN, V1,
                   up_UV + l*64*128,
                   uv_W1 + l*128*64, uv_b1 + l*64,
                   uv_W2 + l*64*192, uv_b2 + l*192, sout, V0);
  }
}

// Round 4
// 5069.493 us; speedup vs baseline: 3.1691x; 1.0412x over previous
//
#include <hip/hip_runtime.h>
#include <hip/hip_bf16.h>
#include <math.h>

#define NN 40000
#define EE 640000
#define GG 16
#define LL 3
#define TE 32

// LDS strides (ushort units)
#define STC 200           // cat rows, K=192
#define STH 136           // h1 rows, K=128
#define STE 72            // es rows, K=64
#define PCAT (TE*STC)     // 6400
#define PH1  (TE*STH)     // 4352
#define PES  (TE*STE)     // 2304
#define SWP_ST 196        // Wphi fp32 stride (overlays sCat: 32*196*4 = 25088B <= 25600B)

typedef __attribute__((ext_vector_type(8))) short s8v;   // 8 bf16
typedef __attribute__((ext_vector_type(4))) float f4v;   // MFMA acc

__device__ __forceinline__ float silu_f(float x){ return x / (1.f + __expf(-x)); }
__device__ __forceinline__ float sigmoid_f(float x){ return 1.f / (1.f + __expf(-x)); }
__device__ __forceinline__ ushort f2b(float x){
  __hip_bfloat16 h = __float2bfloat16(x);
  return __builtin_bit_cast(ushort, h);
}
__device__ __forceinline__ float b2f(ushort u){
  __hip_bfloat16 h = __builtin_bit_cast(__hip_bfloat16, u);
  return __bfloat162float(h);
}

// ---------------- edge geometry: UD[e] = {ux,uy,uz,dist} ----------------
__global__ void k_geom(const float* __restrict__ pos, const int* __restrict__ edges,
                       float4* __restrict__ UD){
  int e = blockIdx.x*blockDim.x + threadIdx.x;
  if(e >= EE) return;
  int s = edges[2*e], d = edges[2*e+1];
  float dx = pos[3*d]-pos[3*s], dy = pos[3*d+1]-pos[3*s+1], dz = pos[3*d+2]-pos[3*s+2];
  float r = sqrtf(dx*dx+dy*dy+dz*dz + 1e-12f);
  float ir = 1.f/r;
  UD[e] = make_float4(dx*ir, dy*ir, dz*ir, r);
}

// ---------------- per-graph node counts ----------------
__global__ void k_counts(const int* __restrict__ gids, int* __restrict__ cnt){
  int n = blockIdx.x*blockDim.x+threadIdx.x;
  if(n<NN) atomicAdd(&cnt[gids[n]], 1);
}

// ---------------- weight prep: transposed hi/lo bf16 planes ----------------
__global__ void k_prep_w(const float* __restrict__ elW1, const float* __restrict__ elW2,
                         const float* __restrict__ inW,
                         ushort* __restrict__ W1H, ushort* __restrict__ W1L,
                         ushort* __restrict__ W2H, ushort* __restrict__ W2L,
                         ushort* __restrict__ W3H, ushort* __restrict__ W3L){
  int tid = blockIdx.x*256 + threadIdx.x;
  const int per = 24576 + 8192 + 12288;
  if(tid >= LL*per) return;
  int l = tid/per, r = tid - l*per;
  float w; ushort* dh; ushort* dl; int idx;
  if(r < 24576){                 // W1t[n][k] = el_W1[k][n], 128x192
    int n = r/192, k = r - n*192;
    w = elW1[l*24576 + k*128 + n];
    dh = W1H; dl = W1L; idx = l*24576 + r;
  } else if(r < 32768){          // W2t[n][k] = el_W2[k][n], 64x128
    int i = r - 24576; int n = i/128, k = i - n*128;
    w = elW2[l*8192 + k*64 + n];
    dh = W2H; dl = W2L; idx = l*8192 + i;
  } else {                       // W3t[n][k] = in_W[k][n], 192x64
    int i = r - 32768; int n = i/64, k = i - n*64;
    w = inW[l*12288 + k*192 + n];
    dh = W3H; dl = W3L; idx = l*12288 + i;
  }
  ushort hi = f2b(w);
  dh[idx] = hi;
  dl[idx] = f2b(w - b2f(hi));
}

// ---------------- initial projection ----------------
__global__ void k_proj(const float* __restrict__ x,
                       const float* __restrict__ W1, const float* __restrict__ b1,
                       const float* __restrict__ W2, const float* __restrict__ b2,
                       float* __restrict__ S){
  int n = blockIdx.x*blockDim.x+threadIdx.x;
  if(n>=NN) return;
  float xr[32];
  #pragma unroll
  for(int k=0;k<32;k++) xr[k] = x[n*32+k];
  float h[32];
  #pragma unroll 4
  for(int j=0;j<32;j++){
    float a = b1[j];
    #pragma unroll
    for(int k=0;k<32;k++) a += xr[k]*W1[k*32+j];
    h[j] = silu_f(a);
  }
  #pragma unroll 4
  for(int d=0; d<64; d++){
    float a = b2[d];
    #pragma unroll
    for(int j=0;j<32;j++) a += h[j]*W2[j*64+d];
    S[n*64+d] = a;
  }
}

// ---------------- graph-LN partial sums ----------------
__global__ void k_ln_reduce(const float* __restrict__ S, const int* __restrict__ gids,
                            float* __restrict__ GS, float* __restrict__ GQ){
  __shared__ float ls[GG], lq[GG];
  int t = threadIdx.x;
  if(t<GG){ ls[t]=0.f; lq[t]=0.f; }
  __syncthreads();
  int n = blockIdx.x*blockDim.x+t;
  if(n<NN){
    const float4* p = reinterpret_cast<const float4*>(S + (size_t)n*64);
    float sm=0.f, sq=0.f;
    #pragma unroll
    for(int i=0;i<16;i++){ float4 v=p[i];
      sm += v.x+v.y+v.z+v.w;
      sq += v.x*v.x+v.y*v.y+v.z*v.z+v.w*v.w; }
    int g = gids[n];
    atomicAdd(&ls[g], sm); atomicAdd(&lq[g], sq);
  }
  __syncthreads();
  if(t<GG){ atomicAdd(&GS[t], ls[t]); atomicAdd(&GQ[t], lq[t]); }
}

__global__ void k_ln_final(const float* __restrict__ GS, const float* __restrict__ GQ,
                           const int* __restrict__ cnt,
                           float* __restrict__ MEANV, float* __restrict__ INVV){
  int g = threadIdx.x;
  if(g<GG){
    float c = (float)cnt[g]*64.f;
    float m = GS[g]/c, e2 = GQ[g]/c;
    MEANV[g]=m; INVV[g]=rsqrtf(e2 - m*m + 1e-5f);
  }
}

// ---------------- node pre: sn -> SN, phi (fp32) ----------------
__global__ void k_node_pre(const float* __restrict__ S, const int* __restrict__ gids,
                           const float* __restrict__ MEANV, const float* __restrict__ INVV,
                           const float* __restrict__ lng, const float* __restrict__ lnb,
                           const float* __restrict__ W1, const float* __restrict__ b1,
                           const float* __restrict__ W2, const float* __restrict__ b2,
                           float* __restrict__ SN, float* __restrict__ PHI){
  int t = threadIdx.x, w = t>>6, lane = t&63;
  int n = blockIdx.x*4 + w;
  __shared__ float sh[4][65];
  __shared__ float hh[4][65];
  if(n < NN){
    int g = gids[n];
    float snv = (S[(size_t)n*64+lane] - MEANV[g]) * INVV[g] * lng[lane] + lnb[lane];
    SN[(size_t)n*64+lane] = snv;
    sh[w][lane] = snv;
  }
  __syncthreads();
  if(n < NN){
    float a = b1[lane];
    #pragma unroll 8
    for(int k=0;k<64;k++) a += sh[w][k]*W1[k*64+lane];
    hh[w][lane] = silu_f(a);
  }
  __syncthreads();
  if(n < NN){
    #pragma unroll
    for(int m=0;m<3;m++){
      int j = lane + 64*m;
      float a = b2[j];
      #pragma unroll 8
      for(int k=0;k<64;k++) a += hh[w][k]*W2[k*192+j];
      PHI[(size_t)n*192+j] = a;
    }
  }
}

// ---------------- fused split-precision MFMA edge kernel (weights in VGPRs) ----------------
__global__ __launch_bounds__(256,2) void k_edge(
    const float* __restrict__ S, const float* __restrict__ PHI,
    const float* __restrict__ V0, const float4* __restrict__ UD,
    const int* __restrict__ edges,
    const float* __restrict__ efW, const float* __restrict__ efb,
    const ushort* __restrict__ GW1H, const ushort* __restrict__ GW1L, const float* __restrict__ elb1,
    const ushort* __restrict__ GW2H, const ushort* __restrict__ GW2L, const float* __restrict__ elb2,
    const ushort* __restrict__ GW3H, const ushort* __restrict__ GW3L, const float* __restrict__ inb,
    const float* __restrict__ eiW, const float* __restrict__ eib,
    float* __restrict__ SN, float* __restrict__ V1)
{
  __shared__ __align__(16) ushort sCat[2*PCAT];   // phase G3+: overlaid by fp32 Wphi[TE][196]
  __shared__ __align__(16) ushort sH1 [2*PH1];
  __shared__ __align__(16) ushort sEs [2*PES];
  __shared__ int   sSrc[TE], sDst[TE];
  __shared__ float sUnit[TE*3];

  const int t  = threadIdx.x;
  const int e0 = blockIdx.x * TE;
  const int w  = t >> 6, l = t & 63;
  const int lr = l & 15, lg = l >> 4;

  // ---- stage edge meta
  if(t < TE){
    int e = e0 + t;
    sSrc[t] = edges[2*e]; sDst[t] = edges[2*e+1];
    float4 ud = UD[e];
    sUnit[3*t] = ud.x; sUnit[3*t+1] = ud.y; sUnit[3*t+2] = ud.z;
  }
  // ---- build cat tile hi/lo: 8 threads per edge, 24 cols each
  {
    int e = t >> 3, sub = t & 7;
    int eg = e0 + e;
    int src = edges[2*eg], dst = edges[2*eg+1];
    float dist = UD[eg].w;
    int j0 = sub*24;
    #pragma unroll
    for(int jj=0;jj<24;jj++){
      int j = j0 + jj;
      float v;
      if(j < 64)       v = S[(size_t)src*64 + j];
      else if(j < 128) v = S[(size_t)dst*64 + (j-64)];
      else             v = silu_f(dist*efW[j-128] + efb[j-128]);
      ushort hi = f2b(v);
      sCat[e*STC + j] = hi;
      sCat[PCAT + e*STC + j] = f2b(v - b2f(hi));
    }
  }
  // ---- W1 B-fragments into registers (wave w owns cols [w*32, w*32+32))
  s8v w1h[2][6], w1l[2][6];
  #pragma unroll
  for(int jl=0;jl<2;jl++){
    #pragma unroll
    for(int k=0;k<6;k++){
      int o = (16*(2*w+jl)+lr)*192 + k*32 + lg*8;
      w1h[jl][k] = *reinterpret_cast<const s8v*>(&GW1H[o]);
      w1l[jl][k] = *reinterpret_cast<const s8v*>(&GW1L[o]);
    }
  }
  __syncthreads();

  // ---- GEMM1: h1 = silu(cat @ W1 + b1)
  #pragma unroll
  for(int rt=0; rt<2; rt++){
    s8v ah[6], al[6];
    #pragma unroll
    for(int k=0;k<6;k++){
      int ro = (16*rt+lr)*STC + k*32 + lg*8;
      ah[k] = *reinterpret_cast<const s8v*>(&sCat[ro]);
      al[k] = *reinterpret_cast<const s8v*>(&sCat[PCAT + ro]);
    }
    #pragma unroll
    for(int jl=0;jl<2;jl++){
      float bv = elb1[16*(2*w+jl)+lr];
      f4v acc = (f4v){bv,bv,bv,bv};
      #pragma unroll
      for(int k=0;k<6;k++){
        acc = __builtin_amdgcn_mfma_f32_16x16x32_bf16(ah[k], w1h[jl][k], acc, 0,0,0);
        acc = __builtin_amdgcn_mfma_f32_16x16x32_bf16(al[k], w1h[jl][k], acc, 0,0,0);
        acc = __builtin_amdgcn_mfma_f32_16x16x32_bf16(ah[k], w1l[jl][k], acc, 0,0,0);
      }
      #pragma unroll
      for(int r=0;r<4;r++){
        float v = silu_f(acc[r]);
        ushort hi = f2b(v);
        int o = (16*rt + lg*4 + r)*STH + 16*(2*w+jl) + lr;
        sH1[o] = hi;
        sH1[PH1 + o] = f2b(v - b2f(hi));
      }
    }
  }
  // ---- W2 / W3 B-fragments into registers
  s8v w2h[4], w2l[4], w3h[3][2], w3l[3][2];
  #pragma unroll
  for(int k=0;k<4;k++){
    int o = (16*w+lr)*128 + k*32 + lg*8;
    w2h[k] = *reinterpret_cast<const s8v*>(&GW2H[o]);
    w2l[k] = *reinterpret_cast<const s8v*>(&GW2L[o]);
  }
  #pragma unroll
  for(int jl=0;jl<3;jl++){
    #pragma unroll
    for(int k=0;k<2;k++){
      int o = (16*(3*w+jl)+lr)*64 + k*32 + lg*8;
      w3h[jl][k] = *reinterpret_cast<const s8v*>(&GW3H[o]);
      w3l[jl][k] = *reinterpret_cast<const s8v*>(&GW3L[o]);
    }
  }
  __syncthreads();

  // ---- GEMM2: es = h1 @ W2 + b2  (wave w owns cols [w*16, w*16+16))
  #pragma unroll
  for(int rt=0; rt<2; rt++){
    s8v a2h[4], a2l[4];
    #pragma unroll
    for(int k=0;k<4;k++){
      int ro = (16*rt+lr)*STH + k*32 + lg*8;
      a2h[k] = *reinterpret_cast<const s8v*>(&sH1[ro]);
      a2l[k] = *reinterpret_cast<const s8v*>(&sH1[PH1 + ro]);
    }
    float bv = elb2[16*w + lr];
    f4v acc = (f4v){bv,bv,bv,bv};
    #pragma unroll
    for(int k=0;k<4;k++){
      acc = __builtin_amdgcn_mfma_f32_16x16x32_bf16(a2h[k], w2h[k], acc, 0,0,0);
      acc = __builtin_amdgcn_mfma_f32_16x16x32_bf16(a2l[k], w2h[k], acc, 0,0,0);
      acc = __builtin_amdgcn_mfma_f32_16x16x32_bf16(a2h[k], w2l[k], acc, 0,0,0);
    }
    #pragma unroll
    for(int r=0;r<4;r++){
      float v = acc[r];
      ushort hi = f2b(v);
      int o = (16*rt + lg*4 + r)*STE + 16*w + lr;
      sEs[o] = hi;
      sEs[PES + o] = f2b(v - b2f(hi));
    }
  }
  __syncthreads();

  // ---- GEMM3: Wv = es @ inW + inb -> fp32 Wphi in LDS (overlay sCat)
  float* sWp = reinterpret_cast<float*>(sCat);
  #pragma unroll
  for(int rt=0; rt<2; rt++){
    s8v a3h[2], a3l[2];
    #pragma unroll
    for(int k=0;k<2;k++){
      int ro = (16*rt+lr)*STE + k*32 + lg*8;
      a3h[k] = *reinterpret_cast<const s8v*>(&sEs[ro]);
      a3l[k] = *reinterpret_cast<const s8v*>(&sEs[PES + ro]);
    }
    #pragma unroll
    for(int jl=0;jl<3;jl++){
      int n = 16*(3*w+jl) + lr;
      float bv = inb[n];
      f4v acc = (f4v){bv,bv,bv,bv};
      #pragma unroll
      for(int k=0;k<2;k++){
        acc = __builtin_amdgcn_mfma_f32_16x16x32_bf16(a3h[k], w3h[jl][k], acc, 0,0,0);
        acc = __builtin_amdgcn_mfma_f32_16x16x32_bf16(a3l[k], w3h[jl][k], acc, 0,0,0);
        acc = __builtin_amdgcn_mfma_f32_16x16x32_bf16(a3h[k], w3l[jl][k], acc, 0,0,0);
      }
      #pragma unroll
      for(int r=0;r<4;r++)
        sWp[(16*rt + lg*4 + r)*SWP_ST + n] = acc[r];
    }
  }
  __syncthreads();

  // ---- scatter: wave w handles edges [w*8, w*8+8), lane l = column l
  #pragma unroll
  for(int i=0;i<8;i++){
    int e = w*8 + i;
    int src = sSrc[e], dst = sDst[e];
    float ps  = sWp[e*SWP_ST + l]       * PHI[(size_t)src*192 + l];
    float pvv = sWp[e*SWP_ST + 64 + l]  * PHI[(size_t)src*192 + 64 + l];
    float pvs = sWp[e*SWP_ST + 128 + l] * PHI[(size_t)src*192 + 128 + l];
    float gp = ps * eiW[l];
    #pragma unroll
    for(int off=1; off<64; off<<=1) gp += __shfl_xor(gp, off);
    float g = sigmoid_f(gp + eib[0]);
    atomicAdd(&SN[(size_t)dst*64 + l], ps*g);
    #pragma unroll
    for(int c=0;c<3;c++){
      float v0 = V0[(size_t)src*192 + c*64 + l];
      atomicAdd(&V1[(size_t)dst*192 + c*64 + l], (v0*pvv + pvs*sUnit[e*3+c])*g);
    }
  }
}

// ---------------- node post: UV update ----------------
__global__ void k_node_post(const float* __restrict__ SN, const float* __restrict__ V1,
                            const float* __restrict__ upUV,
                            const float* __restrict__ uvW1, const float* __restrict__ uvb1,
                            const float* __restrict__ uvW2, const float* __restrict__ uvb2,
                            float* __restrict__ Sout, float* __restrict__ V0)
{
  int t = threadIdx.x, w = t>>6, j = t&63;
  int n = blockIdx.x*4 + w;
  __shared__ float vsh[4][3][64];
  __shared__ float cat2[4][129];
  __shared__ float hh[4][65];
  if(n < NN){
    #pragma unroll
    for(int c=0;c<3;c++) vsh[w][c][j] = V1[(size_t)n*192 + c*64 + j];
  }
  __syncthreads();
  float Uv[3]={0,0,0}, Vv[3]={0,0,0};
  float s_new = 0.f;
  if(n < NN){
    #pragma unroll 4
    for(int k=0;k<64;k++){
      float wu = upUV[k*128 + j];
      float wv = upUV[k*128 + 64 + j];
      #pragma unroll
      for(int c=0;c<3;c++){ float vk = vsh[w][c][k]; Uv[c] += vk*wu; Vv[c] += vk*wv; }
    }
    s_new = SN[(size_t)n*64 + j];
    float vn2 = Vv[0]*Vv[0]+Vv[1]*Vv[1]+Vv[2]*Vv[2];
    cat2[w][j] = sqrtf(vn2 + 1e-6f);
    cat2[w][64+j] = s_new;
  }
  __syncthreads();
  if(n<NN){
    float a = uvb1[j];
    #pragma unroll 8
    for(int k=0;k<128;k++) a += cat2[w][k]*uvW1[k*64+j];
    hh[w][j] = silu_f(a);
  }
  __syncthreads();
  if(n<NN){
    float a0=uvb2[j], a1=uvb2[64+j], a2=uvb2[128+j];
    #pragma unroll 4
    for(int k=0;k<64;k++){
      float h = hh[w][k];
      a0 += h*uvW2[k*192+j]; a1 += h*uvW2[k*192+64+j]; a2 += h*uvW2[k*192+128+j];
    }
    float inner = Uv[0]*Vv[0]+Uv[1]*Vv[1]+Uv[2]*Vv[2];
    Sout[(size_t)n*64+j] = s_new + a2 + a1*inner;
    #pragma unroll
    for(int c=0;c<3;c++) V0[(size_t)n*192 + c*64 + j] = vsh[w][c][j] + a0*Uv[c];
  }
}

extern "C" void kernel_launch(void* const* d_in, const int* in_sizes, int n_in,
                              void* d_out, int out_size, void* d_ws, size_t ws_size,
                              hipStream_t stream)
{
  const float* node_features  = (const float*)d_in[0];
  const float* node_positions = (const float*)d_in[1];
  const int*   edges          = (const int*)  d_in[2];
  const int*   gids           = (const int*)  d_in[3];
  const float* proj_W1 = (const float*)d_in[4];
  const float* proj_b1 = (const float*)d_in[5];
  const float* proj_W2 = (const float*)d_in[6];
  const float* proj_b2 = (const float*)d_in[7];
  const float* ef_W  = (const float*)d_in[8];
  const float* ef_b  = (const float*)d_in[9];
  const float* el_W1 = (const float*)d_in[10];
  const float* el_b1 = (const float*)d_in[11];
  const float* el_W2 = (const float*)d_in[12];
  const float* el_b2 = (const float*)d_in[13];
  const float* in_W  = (const float*)d_in[14];
  const float* in_b  = (const float*)d_in[15];
  const float* msg_W1= (const float*)d_in[16];
  const float* msg_b1= (const float*)d_in[17];
  const float* msg_W2= (const float*)d_in[18];
  const float* msg_b2= (const float*)d_in[19];
  const float* ei_W  = (const float*)d_in[20];
  const float* ei_b  = (const float*)d_in[21];
  const float* ln_g  = (const float*)d_in[22];
  const float* ln_b  = (const float*)d_in[23];
  const float* up_UV = (const float*)d_in[24];
  const float* uv_W1 = (const float*)d_in[25];
  const float* uv_b1 = (const float*)d_in[26];
  const float* uv_W2 = (const float*)d_in[27];
  const float* uv_b2 = (const float*)d_in[28];

  float* ws = (float*)d_ws;
  size_t off = 0;
  float*  S    = ws + off; off += (size_t)NN*64;
  float*  SN   = ws + off; off += (size_t)NN*64;
  float*  PHI  = ws + off; off += (size_t)NN*192;
  float*  V0   = ws + off; off += (size_t)NN*192;
  float*  V1   = ws + off; off += (size_t)NN*192;
  float4* UD   = (float4*)(ws + off); off += (size_t)EE*4;
  float*  GS   = ws + off; off += GG;
  float*  GQ   = ws + off; off += GG;
  float*  MEANV= ws + off; off += GG;
  float*  INVV = ws + off; off += GG;
  int*    CNT  = (int*)(ws + off); off += GG;
  off = (off + 3) & ~(size_t)3;          // 16B-align weight planes
  ushort* W1H = (ushort*)(ws + off); off += (size_t)LL*24576/2;
  ushort* W1L = (ushort*)(ws + off); off += (size_t)LL*24576/2;
  ushort* W2H = (ushort*)(ws + off); off += (size_t)LL*8192/2;
  ushort* W2L = (ushort*)(ws + off); off += (size_t)LL*8192/2;
  ushort* W3H = (ushort*)(ws + off); off += (size_t)LL*12288/2;
  ushort* W3L = (ushort*)(ws + off); off += (size_t)LL*12288/2;

  hipMemsetAsync(CNT, 0, GG*sizeof(int), stream);
  hipMemsetAsync(V0, 0, (size_t)NN*192*sizeof(float), stream);

  k_geom  <<<(EE+255)/256, 256, 0, stream>>>(node_positions, edges, UD);
  k_counts<<<(NN+255)/256, 256, 0, stream>>>(gids, CNT);
  k_proj  <<<(NN+255)/256, 256, 0, stream>>>(node_features, proj_W1, proj_b1, proj_W2, proj_b2, S);
  k_prep_w<<<(LL*45056+255)/256, 256, 0, stream>>>(el_W1, el_W2, in_W, W1H, W1L, W2H, W2L, W3H, W3L);

  for(int l=0; l<LL; l++){
    hipMemsetAsync(GS, 0, 2*GG*sizeof(float), stream);
    k_ln_reduce<<<(NN+255)/256, 256, 0, stream>>>(S, gids, GS, GQ);
    k_ln_final <<<1, 64, 0, stream>>>(GS, GQ, CNT, MEANV, INVV);
    k_node_pre <<<(NN+3)/4, 256, 0, stream>>>(S, gids, MEANV, INVV,
                   ln_g + l*64, ln_b + l*64,
                   msg_W1 + l*64*64, msg_b1 + l*64,
                   msg_W2 + l*64*192, msg_b2 + l*192, SN, PHI);
    hipMemcpyAsync(V1, V0, (size_t)NN*192*sizeof(float), hipMemcpyDeviceToDevice, stream);
    k_edge<<<EE/TE, 256, 0, stream>>>(S, PHI, V0, UD, edges,
                   ef_W + l*64, ef_b + l*64,
                   W1H + l*24576, W1L + l*24576, el_b1 + l*128,
                   W2H + l*8192,  W2L + l*8192,  el_b2 + l*64,
                   W3H + l*12288, W3L + l*12288, in_b + l*192,
                   ei_W + l*64, ei_b + l, SN, V1);
    float* sout = (l == LL-1) ? (float*)d_out : S;
    k_node_post<<<(NN+3)/4, 256, 0, stream>>>(SN, V1,
                   up_UV + l*64*128,
                   uv_W1 + l*128*64, uv_b1 + l*64,
                   uv_W2 + l*64*192, uv_b2 + l*192, sout, V0);
  }
}

// Round 5
// 4307.710 us; speedup vs baseline: 3.7296x; 1.1768x over previous
//
#include <hip/hip_runtime.h>
#include <hip/hip_bf16.h>
#include <math.h>

#define NN 40000
#define EE 640000
#define GG 16
#define LL 3
#define TE 32

// LDS strides (ushort units)
#define STC 200           // cat rows, K=192
#define STH 136           // h1 rows, K=128
#define STE 72            // es rows, K=64
#define PCAT (TE*STC)     // 6400
#define PH1  (TE*STH)     // 4352
#define PES  (TE*STE)     // 2304
#define SWP_ST 196        // Wphi fp32 stride (overlays sCat: 32*196*4 = 25088B <= 25600B)

typedef __attribute__((ext_vector_type(8))) short s8v;   // 8 bf16
typedef __attribute__((ext_vector_type(4))) float f4v;   // MFMA acc

__device__ __forceinline__ float silu_f(float x){ return x / (1.f + __expf(-x)); }
__device__ __forceinline__ float sigmoid_f(float x){ return 1.f / (1.f + __expf(-x)); }
__device__ __forceinline__ ushort f2b(float x){
  __hip_bfloat16 h = __float2bfloat16(x);
  return __builtin_bit_cast(ushort, h);
}
__device__ __forceinline__ float b2f(ushort u){
  __hip_bfloat16 h = __builtin_bit_cast(__hip_bfloat16, u);
  return __bfloat162float(h);
}

// ---------------- edge geometry: UD[e] = {ux,uy,uz,dist} ----------------
__global__ void k_geom(const float* __restrict__ pos, const int* __restrict__ edges,
                       float4* __restrict__ UD){
  int e = blockIdx.x*blockDim.x + threadIdx.x;
  if(e >= EE) return;
  int s = edges[2*e], d = edges[2*e+1];
  float dx = pos[3*d]-pos[3*s], dy = pos[3*d+1]-pos[3*s+1], dz = pos[3*d+2]-pos[3*s+2];
  float r = sqrtf(dx*dx+dy*dy+dz*dz + 1e-12f);
  float ir = 1.f/r;
  UD[e] = make_float4(dx*ir, dy*ir, dz*ir, r);
}

// ---------------- per-graph node counts via binary search (gids sorted) ----------------
__global__ void k_counts(const int* __restrict__ gids, int* __restrict__ cnt){
  __shared__ int lb[GG+1];
  int g = threadIdx.x;
  if(g <= GG){
    int lo=0, hi=NN;
    while(lo<hi){ int m=(lo+hi)>>1; if(gids[m]<g) lo=m+1; else hi=m; }
    lb[g]=lo;
  }
  __syncthreads();
  if(g < GG) cnt[g] = lb[g+1]-lb[g];
}

// ---------------- dst histogram ----------------
__global__ void k_hist(const int* __restrict__ edges, int* __restrict__ HIST){
  int e = blockIdx.x*blockDim.x+threadIdx.x;
  if(e<EE) atomicAdd(&HIST[edges[2*e+1]], 1);
}

// ---------------- exclusive scan of HIST (one block, 256 threads) ----------------
__global__ void k_scan(const int* __restrict__ HIST, int* __restrict__ BASE){
  __shared__ int ps[256];
  int t = threadIdx.x;
  const int CH = (NN+255)/256;   // 157
  int lo = t*CH, hi = lo+CH; if(hi>NN) hi=NN; if(lo>NN) lo=NN;
  int s=0;
  for(int i=lo;i<hi;i++) s += HIST[i];
  ps[t]=s;
  __syncthreads();
  if(t==0){ int run=0; for(int i=0;i<256;i++){ int v=ps[i]; ps[i]=run; run+=v; } }
  __syncthreads();
  int run = ps[t];
  for(int i=lo;i<hi;i++){ BASE[i]=run; run += HIST[i]; }
}

// ---------------- scatter edges into dst-sorted order ----------------
__global__ void k_scatter(const int* __restrict__ edges, const int* __restrict__ BASE,
                          int* __restrict__ CUR, int* __restrict__ EP,
                          int* __restrict__ SRCp, int* __restrict__ DSTp){
  int e = blockIdx.x*blockDim.x+threadIdx.x;
  if(e>=EE) return;
  int d = edges[2*e+1];
  int pos = BASE[d] + atomicAdd(&CUR[d], 1);
  EP[pos]   = e;
  SRCp[pos] = edges[2*e];
  DSTp[pos] = d;
}

// ---------------- weight prep: transposed hi/lo bf16 planes ----------------
__global__ void k_prep_w(const float* __restrict__ elW1, const float* __restrict__ elW2,
                         const float* __restrict__ inW,
                         ushort* __restrict__ W1H, ushort* __restrict__ W1L,
                         ushort* __restrict__ W2H, ushort* __restrict__ W2L,
                         ushort* __restrict__ W3H, ushort* __restrict__ W3L){
  int tid = blockIdx.x*256 + threadIdx.x;
  const int per = 24576 + 8192 + 12288;
  if(tid >= LL*per) return;
  int l = tid/per, r = tid - l*per;
  float w; ushort* dh; ushort* dl; int idx;
  if(r < 24576){                 // W1t[n][k] = el_W1[k][n], 128x192
    int n = r/192, k = r - n*192;
    w = elW1[l*24576 + k*128 + n];
    dh = W1H; dl = W1L; idx = l*24576 + r;
  } else if(r < 32768){          // W2t[n][k] = el_W2[k][n], 64x128
    int i = r - 24576; int n = i/128, k = i - n*128;
    w = elW2[l*8192 + k*64 + n];
    dh = W2H; dl = W2L; idx = l*8192 + i;
  } else {                       // W3t[n][k] = in_W[k][n], 192x64
    int i = r - 32768; int n = i/64, k = i - n*64;
    w = inW[l*12288 + k*192 + n];
    dh = W3H; dl = W3L; idx = l*12288 + i;
  }
  ushort hi = f2b(w);
  dh[idx] = hi;
  dl[idx] = f2b(w - b2f(hi));
}

// ---------------- initial projection ----------------
__global__ void k_proj(const float* __restrict__ x,
                       const float* __restrict__ W1, const float* __restrict__ b1,
                       const float* __restrict__ W2, const float* __restrict__ b2,
                       float* __restrict__ S){
  int n = blockIdx.x*blockDim.x+threadIdx.x;
  if(n>=NN) return;
  float xr[32];
  #pragma unroll
  for(int k=0;k<32;k++) xr[k] = x[n*32+k];
  float h[32];
  #pragma unroll 4
  for(int j=0;j<32;j++){
    float a = b1[j];
    #pragma unroll
    for(int k=0;k<32;k++) a += xr[k]*W1[k*32+j];
    h[j] = silu_f(a);
  }
  #pragma unroll 4
  for(int d=0; d<64; d++){
    float a = b2[d];
    #pragma unroll
    for(int j=0;j<32;j++) a += h[j]*W2[j*64+d];
    S[n*64+d] = a;
  }
}

// ---------------- graph-LN partial sums ----------------
__global__ void k_ln_reduce(const float* __restrict__ S, const int* __restrict__ gids,
                            float* __restrict__ GS, float* __restrict__ GQ){
  __shared__ float ls[GG], lq[GG];
  int t = threadIdx.x;
  if(t<GG){ ls[t]=0.f; lq[t]=0.f; }
  __syncthreads();
  int n = blockIdx.x*blockDim.x+t;
  if(n<NN){
    const float4* p = reinterpret_cast<const float4*>(S + (size_t)n*64);
    float sm=0.f, sq=0.f;
    #pragma unroll
    for(int i=0;i<16;i++){ float4 v=p[i];
      sm += v.x+v.y+v.z+v.w;
      sq += v.x*v.x+v.y*v.y+v.z*v.z+v.w*v.w; }
    int g = gids[n];
    atomicAdd(&ls[g], sm); atomicAdd(&lq[g], sq);
  }
  __syncthreads();
  if(t<GG){ atomicAdd(&GS[t], ls[t]); atomicAdd(&GQ[t], lq[t]); }
}

__global__ void k_ln_final(const float* __restrict__ GS, const float* __restrict__ GQ,
                           const int* __restrict__ cnt,
                           float* __restrict__ MEANV, float* __restrict__ INVV){
  int g = threadIdx.x;
  if(g<GG){
    float c = (float)cnt[g]*64.f;
    float m = GS[g]/c, e2 = GQ[g]/c;
    MEANV[g]=m; INVV[g]=rsqrtf(e2 - m*m + 1e-5f);
  }
}

// ---------------- node pre: sn -> SN, phi (fp32) ----------------
__global__ void k_node_pre(const float* __restrict__ S, const int* __restrict__ gids,
                           const float* __restrict__ MEANV, const float* __restrict__ INVV,
                           const float* __restrict__ lng, const float* __restrict__ lnb,
                           const float* __restrict__ W1, const float* __restrict__ b1,
                           const float* __restrict__ W2, const float* __restrict__ b2,
                           float* __restrict__ SN, float* __restrict__ PHI){
  int t = threadIdx.x, w = t>>6, lane = t&63;
  int n = blockIdx.x*4 + w;
  __shared__ float sh[4][65];
  __shared__ float hh[4][65];
  if(n < NN){
    int g = gids[n];
    float snv = (S[(size_t)n*64+lane] - MEANV[g]) * INVV[g] * lng[lane] + lnb[lane];
    SN[(size_t)n*64+lane] = snv;
    sh[w][lane] = snv;
  }
  __syncthreads();
  if(n < NN){
    float a = b1[lane];
    #pragma unroll 8
    for(int k=0;k<64;k++) a += sh[w][k]*W1[k*64+lane];
    hh[w][lane] = silu_f(a);
  }
  __syncthreads();
  if(n < NN){
    #pragma unroll
    for(int m=0;m<3;m++){
      int j = lane + 64*m;
      float a = b2[j];
      #pragma unroll 8
      for(int k=0;k<64;k++) a += hh[w][k]*W2[k*192+j];
      PHI[(size_t)n*192+j] = a;
    }
  }
}

// ---------------- fused split-precision MFMA edge kernel (dst-sorted) ----------------
__global__ __launch_bounds__(256,2) void k_edge(
    const float* __restrict__ S, const float* __restrict__ PHI,
    const float* __restrict__ V0, const float4* __restrict__ UD,
    const int* __restrict__ EP, const int* __restrict__ SRCp, const int* __restrict__ DSTp,
    const float* __restrict__ efW, const float* __restrict__ efb,
    const ushort* __restrict__ GW1H, const ushort* __restrict__ GW1L, const float* __restrict__ elb1,
    const ushort* __restrict__ GW2H, const ushort* __restrict__ GW2L, const float* __restrict__ elb2,
    const ushort* __restrict__ GW3H, const ushort* __restrict__ GW3L, const float* __restrict__ inb,
    const float* __restrict__ eiW, const float* __restrict__ eib,
    float* __restrict__ SN, float* __restrict__ V1)
{
  __shared__ __align__(16) ushort sCat[2*PCAT];   // later overlaid by fp32 Wphi[TE][SWP_ST]
  __shared__ __align__(16) ushort sH1 [2*PH1];
  __shared__ __align__(16) ushort sEs [2*PES];
  __shared__ int   sSrc[TE], sDst[TE];
  __shared__ float sUnit[TE*3];
  __shared__ float sGate[TE];

  const int t  = threadIdx.x;
  const int p0 = blockIdx.x * TE;
  const int w  = t >> 6, l = t & 63;
  const int lr = l & 15, lg = l >> 4;

  // ---- stage edge meta (sorted order)
  if(t < TE){
    int p = p0 + t;
    sSrc[t] = SRCp[p]; sDst[t] = DSTp[p];
    float4 ud = UD[EP[p]];
    sUnit[3*t] = ud.x; sUnit[3*t+1] = ud.y; sUnit[3*t+2] = ud.z;
  }
  // ---- build cat tile hi/lo: 8 threads per edge, 24 cols each
  {
    int e = t >> 3, sub = t & 7;
    int pg = p0 + e;
    int src = SRCp[pg], dst = DSTp[pg];
    float dist = UD[EP[pg]].w;
    int j0 = sub*24;
    #pragma unroll
    for(int jj=0;jj<24;jj++){
      int j = j0 + jj;
      float v;
      if(j < 64)       v = S[(size_t)src*64 + j];
      else if(j < 128) v = S[(size_t)dst*64 + (j-64)];
      else             v = silu_f(dist*efW[j-128] + efb[j-128]);
      ushort hi = f2b(v);
      sCat[e*STC + j] = hi;
      sCat[PCAT + e*STC + j] = f2b(v - b2f(hi));
    }
  }
  // ---- W1 B-fragments into registers (wave w owns cols [w*32, w*32+32))
  s8v w1h[2][6], w1l[2][6];
  #pragma unroll
  for(int jl=0;jl<2;jl++){
    #pragma unroll
    for(int k=0;k<6;k++){
      int o = (16*(2*w+jl)+lr)*192 + k*32 + lg*8;
      w1h[jl][k] = *reinterpret_cast<const s8v*>(&GW1H[o]);
      w1l[jl][k] = *reinterpret_cast<const s8v*>(&GW1L[o]);
    }
  }
  __syncthreads();

  // ---- GEMM1: h1 = silu(cat @ W1 + b1)
  #pragma unroll
  for(int rt=0; rt<2; rt++){
    s8v ah[6], al[6];
    #pragma unroll
    for(int k=0;k<6;k++){
      int ro = (16*rt+lr)*STC + k*32 + lg*8;
      ah[k] = *reinterpret_cast<const s8v*>(&sCat[ro]);
      al[k] = *reinterpret_cast<const s8v*>(&sCat[PCAT + ro]);
    }
    #pragma unroll
    for(int jl=0;jl<2;jl++){
      float bv = elb1[16*(2*w+jl)+lr];
      f4v acc = (f4v){bv,bv,bv,bv};
      #pragma unroll
      for(int k=0;k<6;k++){
        acc = __builtin_amdgcn_mfma_f32_16x16x32_bf16(ah[k], w1h[jl][k], acc, 0,0,0);
        acc = __builtin_amdgcn_mfma_f32_16x16x32_bf16(al[k], w1h[jl][k], acc, 0,0,0);
        acc = __builtin_amdgcn_mfma_f32_16x16x32_bf16(ah[k], w1l[jl][k], acc, 0,0,0);
      }
      #pragma unroll
      for(int r=0;r<4;r++){
        float v = silu_f(acc[r]);
        ushort hi = f2b(v);
        int o = (16*rt + lg*4 + r)*STH + 16*(2*w+jl) + lr;
        sH1[o] = hi;
        sH1[PH1 + o] = f2b(v - b2f(hi));
      }
    }
  }
  // ---- W2 / W3 B-fragments into registers
  s8v w2h[4], w2l[4], w3h[3][2], w3l[3][2];
  #pragma unroll
  for(int k=0;k<4;k++){
    int o = (16*w+lr)*128 + k*32 + lg*8;
    w2h[k] = *reinterpret_cast<const s8v*>(&GW2H[o]);
    w2l[k] = *reinterpret_cast<const s8v*>(&GW2L[o]);
  }
  #pragma unroll
  for(int jl=0;jl<3;jl++){
    #pragma unroll
    for(int k=0;k<2;k++){
      int o = (16*(3*w+jl)+lr)*64 + k*32 + lg*8;
      w3h[jl][k] = *reinterpret_cast<const s8v*>(&GW3H[o]);
      w3l[jl][k] = *reinterpret_cast<const s8v*>(&GW3L[o]);
    }
  }
  __syncthreads();

  // ---- GEMM2: es = h1 @ W2 + b2  (wave w owns cols [w*16, w*16+16))
  #pragma unroll
  for(int rt=0; rt<2; rt++){
    s8v a2h[4], a2l[4];
    #pragma unroll
    for(int k=0;k<4;k++){
      int ro = (16*rt+lr)*STH + k*32 + lg*8;
      a2h[k] = *reinterpret_cast<const s8v*>(&sH1[ro]);
      a2l[k] = *reinterpret_cast<const s8v*>(&sH1[PH1 + ro]);
    }
    float bv = elb2[16*w + lr];
    f4v acc = (f4v){bv,bv,bv,bv};
    #pragma unroll
    for(int k=0;k<4;k++){
      acc = __builtin_amdgcn_mfma_f32_16x16x32_bf16(a2h[k], w2h[k], acc, 0,0,0);
      acc = __builtin_amdgcn_mfma_f32_16x16x32_bf16(a2l[k], w2h[k], acc, 0,0,0);
      acc = __builtin_amdgcn_mfma_f32_16x16x32_bf16(a2h[k], w2l[k], acc, 0,0,0);
    }
    #pragma unroll
    for(int r=0;r<4;r++){
      float v = acc[r];
      ushort hi = f2b(v);
      int o = (16*rt + lg*4 + r)*STE + 16*w + lr;
      sEs[o] = hi;
      sEs[PES + o] = f2b(v - b2f(hi));
    }
  }
  __syncthreads();

  // ---- GEMM3: Wphi = (es @ inW + inb) * phi[src] -> fp32 in LDS (overlay sCat)
  float* sWp = reinterpret_cast<float*>(sCat);
  #pragma unroll
  for(int rt=0; rt<2; rt++){
    s8v a3h[2], a3l[2];
    #pragma unroll
    for(int k=0;k<2;k++){
      int ro = (16*rt+lr)*STE + k*32 + lg*8;
      a3h[k] = *reinterpret_cast<const s8v*>(&sEs[ro]);
      a3l[k] = *reinterpret_cast<const s8v*>(&sEs[PES + ro]);
    }
    // prefetch phi (exactly once per (edge, col))
    float ph[3][4];
    #pragma unroll
    for(int jl=0;jl<3;jl++){
      int n = 16*(3*w+jl) + lr;
      #pragma unroll
      for(int r=0;r<4;r++){
        int e = 16*rt + lg*4 + r;
        ph[jl][r] = PHI[(size_t)sSrc[e]*192 + n];
      }
    }
    #pragma unroll
    for(int jl=0;jl<3;jl++){
      int n = 16*(3*w+jl) + lr;
      float bv = inb[n];
      f4v acc = (f4v){bv,bv,bv,bv};
      #pragma unroll
      for(int k=0;k<2;k++){
        acc = __builtin_amdgcn_mfma_f32_16x16x32_bf16(a3h[k], w3h[jl][k], acc, 0,0,0);
        acc = __builtin_amdgcn_mfma_f32_16x16x32_bf16(a3l[k], w3h[jl][k], acc, 0,0,0);
        acc = __builtin_amdgcn_mfma_f32_16x16x32_bf16(a3h[k], w3l[jl][k], acc, 0,0,0);
      }
      #pragma unroll
      for(int r=0;r<4;r++)
        sWp[(16*rt + lg*4 + r)*SWP_ST + n] = acc[r]*ph[jl][r];
    }
  }
  __syncthreads();

  // ---- gate per edge: wave w handles edges [8w, 8w+8)
  float ei = eiW[l];
  #pragma unroll
  for(int i=0;i<8;i++){
    int e = w*8 + i;
    float gp = sWp[e*SWP_ST + l] * ei;
    #pragma unroll
    for(int off=1; off<64; off<<=1) gp += __shfl_xor(gp, off);
    if(l==0) sGate[e] = sigmoid_f(gp + eib[0]);
  }
  __syncthreads();

  // ---- column-owner segmented accumulation (dst-sorted runs)
  if(w == 0){
    float acc = 0.f;
    #pragma unroll 8
    for(int p=0;p<TE;p++){
      acc += sWp[p*SWP_ST + l] * sGate[p];
      bool flush = (p==TE-1) || (sDst[p+1] != sDst[p]);
      if(flush){ atomicAdd(&SN[(size_t)sDst[p]*64 + l], acc); acc = 0.f; }
    }
  } else {
    int c = w-1;
    float acc = 0.f;
    #pragma unroll 8
    for(int p=0;p<TE;p++){
      float pvv = sWp[p*SWP_ST + 64 + l];
      float pvs = sWp[p*SWP_ST + 128 + l];
      float v0 = V0[(size_t)sSrc[p]*192 + c*64 + l];
      acc += (v0*pvv + pvs*sUnit[p*3+c]) * sGate[p];
      bool flush = (p==TE-1) || (sDst[p+1] != sDst[p]);
      if(flush){ atomicAdd(&V1[(size_t)sDst[p]*192 + c*64 + l], acc); acc = 0.f; }
    }
  }
}

// ---------------- node post: UV update ----------------
__global__ void k_node_post(const float* __restrict__ SN, const float* __restrict__ V1,
                            const float* __restrict__ upUV,
                            const float* __restrict__ uvW1, const float* __restrict__ uvb1,
                            const float* __restrict__ uvW2, const float* __restrict__ uvb2,
                            float* __restrict__ Sout, float* __restrict__ V0)
{
  int t = threadIdx.x, w = t>>6, j = t&63;
  int n = blockIdx.x*4 + w;
  __shared__ float vsh[4][3][64];
  __shared__ float cat2[4][129];
  __shared__ float hh[4][65];
  if(n < NN){
    #pragma unroll
    for(int c=0;c<3;c++) vsh[w][c][j] = V1[(size_t)n*192 + c*64 + j];
  }
  __syncthreads();
  float Uv[3]={0,0,0}, Vv[3]={0,0,0};
  float s_new = 0.f;
  if(n < NN){
    #pragma unroll 4
    for(int k=0;k<64;k++){
      float wu = upUV[k*128 + j];
      float wv = upUV[k*128 + 64 + j];
      #pragma unroll
      for(int c=0;c<3;c++){ float vk = vsh[w][c][k]; Uv[c] += vk*wu; Vv[c] += vk*wv; }
    }
    s_new = SN[(size_t)n*64 + j];
    float vn2 = Vv[0]*Vv[0]+Vv[1]*Vv[1]+Vv[2]*Vv[2];
    cat2[w][j] = sqrtf(vn2 + 1e-6f);
    cat2[w][64+j] = s_new;
  }
  __syncthreads();
  if(n<NN){
    float a = uvb1[j];
    #pragma unroll 8
    for(int k=0;k<128;k++) a += cat2[w][k]*uvW1[k*64+j];
    hh[w][j] = silu_f(a);
  }
  __syncthreads();
  if(n<NN){
    float a0=uvb2[j], a1=uvb2[64+j], a2=uvb2[128+j];
    #pragma unroll 4
    for(int k=0;k<64;k++){
      float h = hh[w][k];
      a0 += h*uvW2[k*192+j]; a1 += h*uvW2[k*192+64+j]; a2 += h*uvW2[k*192+128+j];
    }
    float inner = Uv[0]*Vv[0]+Uv[1]*Vv[1]+Uv[2]*Vv[2];
    Sout[(size_t)n*64+j] = s_new + a2 + a1*inner;
    #pragma unroll
    for(int c=0;c<3;c++) V0[(size_t)n*192 + c*64 + j] = vsh[w][c][j] + a0*Uv[c];
  }
}

extern "C" void kernel_launch(void* const* d_in, const int* in_sizes, int n_in,
                              void* d_out, int out_size, void* d_ws, size_t ws_size,
                              hipStream_t stream)
{
  const float* node_features  = (const float*)d_in[0];
  const float* node_positions = (const float*)d_in[1];
  const int*   edges          = (const int*)  d_in[2];
  const int*   gids           = (const int*)  d_in[3];
  const float* proj_W1 = (const float*)d_in[4];
  const float* proj_b1 = (const float*)d_in[5];
  const float* proj_W2 = (const float*)d_in[6];
  const float* proj_b2 = (const float*)d_in[7];
  const float* ef_W  = (const float*)d_in[8];
  const float* ef_b  = (const float*)d_in[9];
  const float* el_W1 = (const float*)d_in[10];
  const float* el_b1 = (const float*)d_in[11];
  const float* el_W2 = (const float*)d_in[12];
  const float* el_b2 = (const float*)d_in[13];
  const float* in_W  = (const float*)d_in[14];
  const float* in_b  = (const float*)d_in[15];
  const float* msg_W1= (const float*)d_in[16];
  const float* msg_b1= (const float*)d_in[17];
  const float* msg_W2= (const float*)d_in[18];
  const float* msg_b2= (const float*)d_in[19];
  const float* ei_W  = (const float*)d_in[20];
  const float* ei_b  = (const float*)d_in[21];
  const float* ln_g  = (const float*)d_in[22];
  const float* ln_b  = (const float*)d_in[23];
  const float* up_UV = (const float*)d_in[24];
  const float* uv_W1 = (const float*)d_in[25];
  const float* uv_b1 = (const float*)d_in[26];
  const float* uv_W2 = (const float*)d_in[27];
  const float* uv_b2 = (const float*)d_in[28];

  float* ws = (float*)d_ws;
  size_t off = 0;
  float*  S    = ws + off; off += (size_t)NN*64;
  float*  SN   = ws + off; off += (size_t)NN*64;
  float*  PHI  = ws + off; off += (size_t)NN*192;
  float*  V0   = ws + off; off += (size_t)NN*192;
  float*  V1   = ws + off; off += (size_t)NN*192;
  float4* UD   = (float4*)(ws + off); off += (size_t)EE*4;
  float*  GS   = ws + off; off += GG;
  float*  GQ   = ws + off; off += GG;
  float*  MEANV= ws + off; off += GG;
  float*  INVV = ws + off; off += GG;
  int*    CNT  = (int*)(ws + off); off += GG;
  off = (off + 3) & ~(size_t)3;          // 16B-align
  ushort* W1H = (ushort*)(ws + off); off += (size_t)LL*24576/2;
  ushort* W1L = (ushort*)(ws + off); off += (size_t)LL*24576/2;
  ushort* W2H = (ushort*)(ws + off); off += (size_t)LL*8192/2;
  ushort* W2L = (ushort*)(ws + off); off += (size_t)LL*8192/2;
  ushort* W3H = (ushort*)(ws + off); off += (size_t)LL*12288/2;
  ushort* W3L = (ushort*)(ws + off); off += (size_t)LL*12288/2;
  int*    HIST = (int*)(ws + off); off += NN;
  int*    BASE = (int*)(ws + off); off += NN;
  int*    CUR  = (int*)(ws + off); off += NN;
  int*    EP   = (int*)(ws + off); off += EE;
  int*    SRCp = (int*)(ws + off); off += EE;
  int*    DSTp = (int*)(ws + off); off += EE;

  hipMemsetAsync(HIST, 0, NN*sizeof(int), stream);
  hipMemsetAsync(CUR,  0, NN*sizeof(int), stream);
  hipMemsetAsync(V0, 0, (size_t)NN*192*sizeof(float), stream);

  k_geom   <<<(EE+255)/256, 256, 0, stream>>>(node_positions, edges, UD);
  k_counts <<<1, 32, 0, stream>>>(gids, CNT);
  k_proj   <<<(NN+255)/256, 256, 0, stream>>>(node_features, proj_W1, proj_b1, proj_W2, proj_b2, S);
  k_prep_w <<<(LL*45056+255)/256, 256, 0, stream>>>(el_W1, el_W2, in_W, W1H, W1L, W2H, W2L, W3H, W3L);
  k_hist   <<<(EE+255)/256, 256, 0, stream>>>(edges, HIST);
  k_scan   <<<1, 256, 0, stream>>>(HIST, BASE);
  k_scatter<<<(EE+255)/256, 256, 0, stream>>>(edges, BASE, CUR, EP, SRCp, DSTp);

  for(int l=0; l<LL; l++){
    hipMemsetAsync(GS, 0, 2*GG*sizeof(float), stream);
    k_ln_reduce<<<(NN+255)/256, 256, 0, stream>>>(S, gids, GS, GQ);
    k_ln_final <<<1, 64, 0, stream>>>(GS, GQ, CNT, MEANV, INVV);
    k_node_pre <<<(NN+3)/4, 256, 0, stream>>>(S, gids, MEANV, INVV,
                   ln_g + l*64, ln_b + l*64,
                   msg_W1 + l*64*64, msg_b1 + l*64,
                   msg_W2 + l*64*192, msg_b2 + l*192, SN, PHI);
    hipMemcpyAsync(V1, V0, (size_t)NN*192*sizeof(float), hipMemcpyDeviceToDevice, stream);
    k_edge<<<EE/TE, 256, 0, stream>>>(S, PHI, V0, UD, EP, SRCp, DSTp,
                   ef_W + l*64, ef_b + l*64,
                   W1H + l*24576, W1L + l*24576, el_b1 + l*128,
                   W2H + l*8192,  W2L + l*8192,  el_b2 + l*64,
                   W3H + l*12288, W3L + l*12288, in_b + l*192,
                   ei_W + l*64, ei_b + l, SN, V1);
    float* sout = (l == LL-1) ? (float*)d_out : S;
    k_node_post<<<(NN+3)/4, 256, 0, stream>>>(SN, V1,
                   up_UV + l*64*128,
                   uv_W1 + l*128*64, uv_b1 + l*64,
                   uv_W2 + l*64*192, uv_b2 + l*192, sout, V0);
  }
}

// Round 6
// 3121.518 us; speedup vs baseline: 5.1468x; 1.3800x over previous
//
#include <hip/hip_runtime.h>
#include <hip/hip_bf16.h>
#include <math.h>

#define NN 40000
#define EE 640000
#define GG 16
#define LL 3
#define TE 32

// LDS strides (ushort units)
#define STC 200           // cat rows, K=192
#define STH 136           // h1 rows, K=128
#define STE 72            // es rows, K=64
#define PCAT (TE*STC)     // 6400
#define PH1  (TE*STH)     // 4352
#define PES  (TE*STE)     // 2304
#define SWP_ST 196        // Wphi fp32 stride (overlays sCat: 32*196*4 = 25088B <= 25600B)

typedef __attribute__((ext_vector_type(8))) short s8v;   // 8 bf16
typedef __attribute__((ext_vector_type(4))) float f4v;   // MFMA acc

__device__ __forceinline__ float silu_f(float x){ return x / (1.f + __expf(-x)); }
__device__ __forceinline__ float sigmoid_f(float x){ return 1.f / (1.f + __expf(-x)); }
__device__ __forceinline__ ushort f2b(float x){
  __hip_bfloat16 h = __float2bfloat16(x);
  return __builtin_bit_cast(ushort, h);
}
__device__ __forceinline__ float b2f(ushort u){
  __hip_bfloat16 h = __builtin_bit_cast(__hip_bfloat16, u);
  return __bfloat162float(h);
}

// ---------------- edge geometry: UD[e] = {ux,uy,uz,dist} ----------------
__global__ void k_geom(const float* __restrict__ pos, const int* __restrict__ edges,
                       float4* __restrict__ UD){
  int e = blockIdx.x*blockDim.x + threadIdx.x;
  if(e >= EE) return;
  int s = edges[2*e], d = edges[2*e+1];
  float dx = pos[3*d]-pos[3*s], dy = pos[3*d+1]-pos[3*s+1], dz = pos[3*d+2]-pos[3*s+2];
  float r = sqrtf(dx*dx+dy*dy+dz*dz + 1e-12f);
  float ir = 1.f/r;
  UD[e] = make_float4(dx*ir, dy*ir, dz*ir, r);
}

// ---------------- per-graph node counts via binary search (gids sorted) ----------------
__global__ void k_counts(const int* __restrict__ gids, int* __restrict__ cnt){
  __shared__ int lb[GG+1];
  int g = threadIdx.x;
  if(g <= GG){
    int lo=0, hi=NN;
    while(lo<hi){ int m=(lo+hi)>>1; if(gids[m]<g) lo=m+1; else hi=m; }
    lb[g]=lo;
  }
  __syncthreads();
  if(g < GG) cnt[g] = lb[g+1]-lb[g];
}

// ---------------- dst histogram ----------------
__global__ void k_hist(const int* __restrict__ edges, int* __restrict__ HIST){
  int e = blockIdx.x*blockDim.x+threadIdx.x;
  if(e<EE) atomicAdd(&HIST[edges[2*e+1]], 1);
}

// ---------------- exclusive scan of HIST (one block, 256 threads) ----------------
__global__ void k_scan(const int* __restrict__ HIST, int* __restrict__ BASE){
  __shared__ int ps[256];
  int t = threadIdx.x;
  const int CH = (NN+255)/256;
  int lo = t*CH, hi = lo+CH; if(hi>NN) hi=NN; if(lo>NN) lo=NN;
  int s=0;
  for(int i=lo;i<hi;i++) s += HIST[i];
  ps[t]=s;
  __syncthreads();
  if(t==0){ int run=0; for(int i=0;i<256;i++){ int v=ps[i]; ps[i]=run; run+=v; } }
  __syncthreads();
  int run = ps[t];
  for(int i=lo;i<hi;i++){ BASE[i]=run; run += HIST[i]; }
}

// ---------------- scatter edges into dst-sorted order (+ sorted UD copy) ----------------
__global__ void k_scatter(const int* __restrict__ edges, const int* __restrict__ BASE,
                          int* __restrict__ CUR,
                          int* __restrict__ SRCp, int* __restrict__ DSTp,
                          const float4* __restrict__ UD, float4* __restrict__ UDP){
  int e = blockIdx.x*blockDim.x+threadIdx.x;
  if(e>=EE) return;
  int d = edges[2*e+1];
  int pos = BASE[d] + atomicAdd(&CUR[d], 1);
  SRCp[pos] = edges[2*e];
  DSTp[pos] = d;
  UDP[pos]  = UD[e];
}

// ---------------- weight prep: transposed hi/lo bf16 planes ----------------
__global__ void k_prep_w(const float* __restrict__ elW1, const float* __restrict__ elW2,
                         const float* __restrict__ inW,
                         ushort* __restrict__ W1H, ushort* __restrict__ W1L,
                         ushort* __restrict__ W2H, ushort* __restrict__ W2L,
                         ushort* __restrict__ W3H, ushort* __restrict__ W3L){
  int tid = blockIdx.x*256 + threadIdx.x;
  const int per = 24576 + 8192 + 12288;
  if(tid >= LL*per) return;
  int l = tid/per, r = tid - l*per;
  float w; ushort* dh; ushort* dl; int idx;
  if(r < 24576){                 // W1t[n][k] = el_W1[k][n], 128x192
    int n = r/192, k = r - n*192;
    w = elW1[l*24576 + k*128 + n];
    dh = W1H; dl = W1L; idx = l*24576 + r;
  } else if(r < 32768){          // W2t[n][k] = el_W2[k][n], 64x128
    int i = r - 24576; int n = i/128, k = i - n*128;
    w = elW2[l*8192 + k*64 + n];
    dh = W2H; dl = W2L; idx = l*8192 + i;
  } else {                       // W3t[n][k] = in_W[k][n], 192x64
    int i = r - 32768; int n = i/64, k = i - n*64;
    w = inW[l*12288 + k*192 + n];
    dh = W3H; dl = W3L; idx = l*12288 + i;
  }
  ushort hi = f2b(w);
  dh[idx] = hi;
  dl[idx] = f2b(w - b2f(hi));
}

// ---------------- initial projection (+ SH/SL planes) ----------------
__global__ void k_proj(const float* __restrict__ x,
                       const float* __restrict__ W1, const float* __restrict__ b1,
                       const float* __restrict__ W2, const float* __restrict__ b2,
                       float* __restrict__ S, ushort* __restrict__ SH, ushort* __restrict__ SL){
  int n = blockIdx.x*blockDim.x+threadIdx.x;
  if(n>=NN) return;
  float xr[32];
  #pragma unroll
  for(int k=0;k<32;k++) xr[k] = x[n*32+k];
  float h[32];
  #pragma unroll 4
  for(int j=0;j<32;j++){
    float a = b1[j];
    #pragma unroll
    for(int k=0;k<32;k++) a += xr[k]*W1[k*32+j];
    h[j] = silu_f(a);
  }
  #pragma unroll 4
  for(int d=0; d<64; d++){
    float a = b2[d];
    #pragma unroll
    for(int j=0;j<32;j++) a += h[j]*W2[j*64+d];
    S[n*64+d] = a;
    ushort hi = f2b(a);
    SH[n*64+d] = hi;
    SL[n*64+d] = f2b(a - b2f(hi));
  }
}

// ---------------- graph-LN partial sums ----------------
__global__ void k_ln_reduce(const float* __restrict__ S, const int* __restrict__ gids,
                            float* __restrict__ GS, float* __restrict__ GQ){
  __shared__ float ls[GG], lq[GG];
  int t = threadIdx.x;
  if(t<GG){ ls[t]=0.f; lq[t]=0.f; }
  __syncthreads();
  int n = blockIdx.x*blockDim.x+t;
  if(n<NN){
    const float4* p = reinterpret_cast<const float4*>(S + (size_t)n*64);
    float sm=0.f, sq=0.f;
    #pragma unroll
    for(int i=0;i<16;i++){ float4 v=p[i];
      sm += v.x+v.y+v.z+v.w;
      sq += v.x*v.x+v.y*v.y+v.z*v.z+v.w*v.w; }
    int g = gids[n];
    atomicAdd(&ls[g], sm); atomicAdd(&lq[g], sq);
  }
  __syncthreads();
  if(t<GG){ atomicAdd(&GS[t], ls[t]); atomicAdd(&GQ[t], lq[t]); }
}

__global__ void k_ln_final(const float* __restrict__ GS, const float* __restrict__ GQ,
                           const int* __restrict__ cnt,
                           float* __restrict__ MEANV, float* __restrict__ INVV){
  int g = threadIdx.x;
  if(g<GG){
    float c = (float)cnt[g]*64.f;
    float m = GS[g]/c, e2 = GQ[g]/c;
    MEANV[g]=m; INVV[g]=rsqrtf(e2 - m*m + 1e-5f);
  }
}

// ---------------- node pre: sn -> SN, phi (bf16) ----------------
__global__ void k_node_pre(const float* __restrict__ S, const int* __restrict__ gids,
                           const float* __restrict__ MEANV, const float* __restrict__ INVV,
                           const float* __restrict__ lng, const float* __restrict__ lnb,
                           const float* __restrict__ W1, const float* __restrict__ b1,
                           const float* __restrict__ W2, const float* __restrict__ b2,
                           float* __restrict__ SN, ushort* __restrict__ PHIb){
  int t = threadIdx.x, w = t>>6, lane = t&63;
  int n = blockIdx.x*4 + w;
  __shared__ float sh[4][65];
  __shared__ float hh[4][65];
  if(n < NN){
    int g = gids[n];
    float snv = (S[(size_t)n*64+lane] - MEANV[g]) * INVV[g] * lng[lane] + lnb[lane];
    SN[(size_t)n*64+lane] = snv;
    sh[w][lane] = snv;
  }
  __syncthreads();
  if(n < NN){
    float a = b1[lane];
    #pragma unroll 8
    for(int k=0;k<64;k++) a += sh[w][k]*W1[k*64+lane];
    hh[w][lane] = silu_f(a);
  }
  __syncthreads();
  if(n < NN){
    #pragma unroll
    for(int m=0;m<3;m++){
      int j = lane + 64*m;
      float a = b2[j];
      #pragma unroll 8
      for(int k=0;k<64;k++) a += hh[w][k]*W2[k*192+j];
      PHIb[(size_t)n*192+j] = f2b(a);
    }
  }
}

// ---------------- fused split-precision MFMA edge kernel (dst-sorted, bf16 gathers) ----------------
__global__ __launch_bounds__(256,3) void k_edge(
    const ushort* __restrict__ SH, const ushort* __restrict__ SL,
    const ushort* __restrict__ PHIb, const ushort* __restrict__ V0b,
    const float4* __restrict__ UDP,
    const int* __restrict__ SRCp, const int* __restrict__ DSTp,
    const float* __restrict__ efW, const float* __restrict__ efb,
    const ushort* __restrict__ GW1H, const ushort* __restrict__ GW1L, const float* __restrict__ elb1,
    const ushort* __restrict__ GW2H, const ushort* __restrict__ GW2L, const float* __restrict__ elb2,
    const ushort* __restrict__ GW3H, const ushort* __restrict__ GW3L, const float* __restrict__ inb,
    const float* __restrict__ eiW, const float* __restrict__ eib,
    float* __restrict__ SN, float* __restrict__ V1)
{
  __shared__ __align__(16) ushort sCat[2*PCAT];   // later overlaid by fp32 Wphi[TE][SWP_ST]
  __shared__ __align__(16) ushort sH1 [2*PH1];
  __shared__ __align__(16) ushort sEs [2*PES];
  __shared__ int   sSrc[TE], sDst[TE];
  __shared__ float sUnit[TE*3];
  __shared__ float sGate[TE];

  const int t  = threadIdx.x;
  const int p0 = blockIdx.x * TE;
  const int w  = t >> 6, l = t & 63;
  const int lr = l & 15, lg = l >> 4;

  // ---- PHIb register prefetch (addresses from sorted SRCp, no barrier needed)
  uint phu[2][3][4];
  #pragma unroll
  for(int rt=0;rt<2;rt++){
    #pragma unroll
    for(int r=0;r<4;r++){
      int srcp = SRCp[p0 + 16*rt + lg*4 + r];
      #pragma unroll
      for(int jl=0;jl<3;jl++)
        phu[rt][jl][r] = PHIb[(size_t)srcp*192 + 16*(3*w+jl) + lr];
    }
  }

  // ---- stage edge meta (sorted order)
  if(t < TE){
    int p = p0 + t;
    sSrc[t] = SRCp[p]; sDst[t] = DSTp[p];
    float4 ud = UDP[p];
    sUnit[3*t] = ud.x; sUnit[3*t+1] = ud.y; sUnit[3*t+2] = ud.z;
  }
  // ---- build cat tile hi/lo: 8 threads per edge, vector copies from SH/SL + es compute
  {
    int e = t >> 3, s = t & 7;
    int pg = p0 + e;
    int src = SRCp[pg], dst = DSTp[pg];
    float dist = UDP[pg].w;
    *reinterpret_cast<s8v*>(&sCat[e*STC + s*8]) =
        *reinterpret_cast<const s8v*>(&SH[(size_t)src*64 + s*8]);
    *reinterpret_cast<s8v*>(&sCat[PCAT + e*STC + s*8]) =
        *reinterpret_cast<const s8v*>(&SL[(size_t)src*64 + s*8]);
    *reinterpret_cast<s8v*>(&sCat[e*STC + 64 + s*8]) =
        *reinterpret_cast<const s8v*>(&SH[(size_t)dst*64 + s*8]);
    *reinterpret_cast<s8v*>(&sCat[PCAT + e*STC + 64 + s*8]) =
        *reinterpret_cast<const s8v*>(&SL[(size_t)dst*64 + s*8]);
    #pragma unroll
    for(int jj=0;jj<8;jj++){
      int j = s*8 + jj;
      float v = silu_f(dist*efW[j] + efb[j]);
      ushort hi = f2b(v);
      sCat[e*STC + 128 + j] = hi;
      sCat[PCAT + e*STC + 128 + j] = f2b(v - b2f(hi));
    }
  }
  // ---- W1 B-fragments into registers (wave w owns cols [w*32, w*32+32))
  s8v w1h[2][6], w1l[2][6];
  #pragma unroll
  for(int jl=0;jl<2;jl++){
    #pragma unroll
    for(int k=0;k<6;k++){
      int o = (16*(2*w+jl)+lr)*192 + k*32 + lg*8;
      w1h[jl][k] = *reinterpret_cast<const s8v*>(&GW1H[o]);
      w1l[jl][k] = *reinterpret_cast<const s8v*>(&GW1L[o]);
    }
  }
  __syncthreads();

  // ---- GEMM1: h1 = silu(cat @ W1 + b1)
  #pragma unroll
  for(int rt=0; rt<2; rt++){
    s8v ah[6], al[6];
    #pragma unroll
    for(int k=0;k<6;k++){
      int ro = (16*rt+lr)*STC + k*32 + lg*8;
      ah[k] = *reinterpret_cast<const s8v*>(&sCat[ro]);
      al[k] = *reinterpret_cast<const s8v*>(&sCat[PCAT + ro]);
    }
    #pragma unroll
    for(int jl=0;jl<2;jl++){
      float bv = elb1[16*(2*w+jl)+lr];
      f4v acc = (f4v){bv,bv,bv,bv};
      #pragma unroll
      for(int k=0;k<6;k++){
        acc = __builtin_amdgcn_mfma_f32_16x16x32_bf16(ah[k], w1h[jl][k], acc, 0,0,0);
        acc = __builtin_amdgcn_mfma_f32_16x16x32_bf16(al[k], w1h[jl][k], acc, 0,0,0);
        acc = __builtin_amdgcn_mfma_f32_16x16x32_bf16(ah[k], w1l[jl][k], acc, 0,0,0);
      }
      #pragma unroll
      for(int r=0;r<4;r++){
        float v = silu_f(acc[r]);
        ushort hi = f2b(v);
        int o = (16*rt + lg*4 + r)*STH + 16*(2*w+jl) + lr;
        sH1[o] = hi;
        sH1[PH1 + o] = f2b(v - b2f(hi));
      }
    }
  }
  // ---- W2 / W3 B-fragments into registers
  s8v w2h[4], w2l[4], w3h[3][2], w3l[3][2];
  #pragma unroll
  for(int k=0;k<4;k++){
    int o = (16*w+lr)*128 + k*32 + lg*8;
    w2h[k] = *reinterpret_cast<const s8v*>(&GW2H[o]);
    w2l[k] = *reinterpret_cast<const s8v*>(&GW2L[o]);
  }
  #pragma unroll
  for(int jl=0;jl<3;jl++){
    #pragma unroll
    for(int k=0;k<2;k++){
      int o = (16*(3*w+jl)+lr)*64 + k*32 + lg*8;
      w3h[jl][k] = *reinterpret_cast<const s8v*>(&GW3H[o]);
      w3l[jl][k] = *reinterpret_cast<const s8v*>(&GW3L[o]);
    }
  }
  __syncthreads();

  // ---- GEMM2: es = h1 @ W2 + b2  (wave w owns cols [w*16, w*16+16))
  #pragma unroll
  for(int rt=0; rt<2; rt++){
    s8v a2h[4], a2l[4];
    #pragma unroll
    for(int k=0;k<4;k++){
      int ro = (16*rt+lr)*STH + k*32 + lg*8;
      a2h[k] = *reinterpret_cast<const s8v*>(&sH1[ro]);
      a2l[k] = *reinterpret_cast<const s8v*>(&sH1[PH1 + ro]);
    }
    float bv = elb2[16*w + lr];
    f4v acc = (f4v){bv,bv,bv,bv};
    #pragma unroll
    for(int k=0;k<4;k++){
      acc = __builtin_amdgcn_mfma_f32_16x16x32_bf16(a2h[k], w2h[k], acc, 0,0,0);
      acc = __builtin_amdgcn_mfma_f32_16x16x32_bf16(a2l[k], w2h[k], acc, 0,0,0);
      acc = __builtin_amdgcn_mfma_f32_16x16x32_bf16(a2h[k], w2l[k], acc, 0,0,0);
    }
    #pragma unroll
    for(int r=0;r<4;r++){
      float v = acc[r];
      ushort hi = f2b(v);
      int o = (16*rt + lg*4 + r)*STE + 16*w + lr;
      sEs[o] = hi;
      sEs[PES + o] = f2b(v - b2f(hi));
    }
  }
  __syncthreads();

  // ---- GEMM3: Wphi = (es @ inW + inb) * phi[src] -> fp32 in LDS (overlay sCat)
  float* sWp = reinterpret_cast<float*>(sCat);
  #pragma unroll
  for(int rt=0; rt<2; rt++){
    s8v a3h[2], a3l[2];
    #pragma unroll
    for(int k=0;k<2;k++){
      int ro = (16*rt+lr)*STE + k*32 + lg*8;
      a3h[k] = *reinterpret_cast<const s8v*>(&sEs[ro]);
      a3l[k] = *reinterpret_cast<const s8v*>(&sEs[PES + ro]);
    }
    #pragma unroll
    for(int jl=0;jl<3;jl++){
      int n = 16*(3*w+jl) + lr;
      float bv = inb[n];
      f4v acc = (f4v){bv,bv,bv,bv};
      #pragma unroll
      for(int k=0;k<2;k++){
        acc = __builtin_amdgcn_mfma_f32_16x16x32_bf16(a3h[k], w3h[jl][k], acc, 0,0,0);
        acc = __builtin_amdgcn_mfma_f32_16x16x32_bf16(a3l[k], w3h[jl][k], acc, 0,0,0);
        acc = __builtin_amdgcn_mfma_f32_16x16x32_bf16(a3h[k], w3l[jl][k], acc, 0,0,0);
      }
      #pragma unroll
      for(int r=0;r<4;r++)
        sWp[(16*rt + lg*4 + r)*SWP_ST + n] = acc[r]*b2f((ushort)phu[rt][jl][r]);
    }
  }
  __syncthreads();

  // ---- gate per edge: wave w handles edges [8w, 8w+8)
  float ei = eiW[l];
  #pragma unroll
  for(int i=0;i<8;i++){
    int e = w*8 + i;
    float gp = sWp[e*SWP_ST + l] * ei;
    #pragma unroll
    for(int off=1; off<64; off<<=1) gp += __shfl_xor(gp, off);
    if(l==0) sGate[e] = sigmoid_f(gp + eib[0]);
  }
  __syncthreads();

  // ---- column-owner segmented accumulation (dst-sorted runs)
  if(w == 0){
    float acc = 0.f;
    #pragma unroll 8
    for(int p=0;p<TE;p++){
      acc += sWp[p*SWP_ST + l] * sGate[p];
      bool flush = (p==TE-1) || (sDst[p+1] != sDst[p]);
      if(flush){ atomicAdd(&SN[(size_t)sDst[p]*64 + l], acc); acc = 0.f; }
    }
  } else {
    int c = w-1;
    float acc = 0.f;
    #pragma unroll 8
    for(int p=0;p<TE;p++){
      float pvv = sWp[p*SWP_ST + 64 + l];
      float pvs = sWp[p*SWP_ST + 128 + l];
      float v0 = b2f(V0b[(size_t)sSrc[p]*192 + c*64 + l]);
      acc += (v0*pvv + pvs*sUnit[p*3+c]) * sGate[p];
      bool flush = (p==TE-1) || (sDst[p+1] != sDst[p]);
      if(flush){ atomicAdd(&V1[(size_t)sDst[p]*192 + c*64 + l], acc); acc = 0.f; }
    }
  }
}

// ---------------- node post: UV update (+ SH/SL/V0b mirrors) ----------------
__global__ void k_node_post(const float* __restrict__ SN, const float* __restrict__ V1,
                            const float* __restrict__ upUV,
                            const float* __restrict__ uvW1, const float* __restrict__ uvb1,
                            const float* __restrict__ uvW2, const float* __restrict__ uvb2,
                            float* __restrict__ Sout, float* __restrict__ V0,
                            ushort* __restrict__ SH, ushort* __restrict__ SL,
                            ushort* __restrict__ V0b)
{
  int t = threadIdx.x, w = t>>6, j = t&63;
  int n = blockIdx.x*4 + w;
  __shared__ float vsh[4][3][64];
  __shared__ float cat2[4][129];
  __shared__ float hh[4][65];
  if(n < NN){
    #pragma unroll
    for(int c=0;c<3;c++) vsh[w][c][j] = V1[(size_t)n*192 + c*64 + j];
  }
  __syncthreads();
  float Uv[3]={0,0,0}, Vv[3]={0,0,0};
  float s_new = 0.f;
  if(n < NN){
    #pragma unroll 4
    for(int k=0;k<64;k++){
      float wu = upUV[k*128 + j];
      float wv = upUV[k*128 + 64 + j];
      #pragma unroll
      for(int c=0;c<3;c++){ float vk = vsh[w][c][k]; Uv[c] += vk*wu; Vv[c] += vk*wv; }
    }
    s_new = SN[(size_t)n*64 + j];
    float vn2 = Vv[0]*Vv[0]+Vv[1]*Vv[1]+Vv[2]*Vv[2];
    cat2[w][j] = sqrtf(vn2 + 1e-6f);
    cat2[w][64+j] = s_new;
  }
  __syncthreads();
  if(n<NN){
    float a = uvb1[j];
    #pragma unroll 8
    for(int k=0;k<128;k++) a += cat2[w][k]*uvW1[k*64+j];
    hh[w][j] = silu_f(a);
  }
  __syncthreads();
  if(n<NN){
    float a0=uvb2[j], a1=uvb2[64+j], a2=uvb2[128+j];
    #pragma unroll 4
    for(int k=0;k<64;k++){
      float h = hh[w][k];
      a0 += h*uvW2[k*192+j]; a1 += h*uvW2[k*192+64+j]; a2 += h*uvW2[k*192+128+j];
    }
    float inner = Uv[0]*Vv[0]+Uv[1]*Vv[1]+Uv[2]*Vv[2];
    float sval = s_new + a2 + a1*inner;
    Sout[(size_t)n*64+j] = sval;
    ushort hi = f2b(sval);
    SH[(size_t)n*64+j] = hi;
    SL[(size_t)n*64+j] = f2b(sval - b2f(hi));
    #pragma unroll
    for(int c=0;c<3;c++){
      float vv = vsh[w][c][j] + a0*Uv[c];
      V0[(size_t)n*192 + c*64 + j] = vv;
      V0b[(size_t)n*192 + c*64 + j] = f2b(vv);
    }
  }
}

extern "C" void kernel_launch(void* const* d_in, const int* in_sizes, int n_in,
                              void* d_out, int out_size, void* d_ws, size_t ws_size,
                              hipStream_t stream)
{
  const float* node_features  = (const float*)d_in[0];
  const float* node_positions = (const float*)d_in[1];
  const int*   edges          = (const int*)  d_in[2];
  const int*   gids           = (const int*)  d_in[3];
  const float* proj_W1 = (const float*)d_in[4];
  const float* proj_b1 = (const float*)d_in[5];
  const float* proj_W2 = (const float*)d_in[6];
  const float* proj_b2 = (const float*)d_in[7];
  const float* ef_W  = (const float*)d_in[8];
  const float* ef_b  = (const float*)d_in[9];
  const float* el_W1 = (const float*)d_in[10];
  const float* el_b1 = (const float*)d_in[11];
  const float* el_W2 = (const float*)d_in[12];
  const float* el_b2 = (const float*)d_in[13];
  const float* in_W  = (const float*)d_in[14];
  const float* in_b  = (const float*)d_in[15];
  const float* msg_W1= (const float*)d_in[16];
  const float* msg_b1= (const float*)d_in[17];
  const float* msg_W2= (const float*)d_in[18];
  const float* msg_b2= (const float*)d_in[19];
  const float* ei_W  = (const float*)d_in[20];
  const float* ei_b  = (const float*)d_in[21];
  const float* ln_g  = (const float*)d_in[22];
  const float* ln_b  = (const float*)d_in[23];
  const float* up_UV = (const float*)d_in[24];
  const float* uv_W1 = (const float*)d_in[25];
  const float* uv_b1 = (const float*)d_in[26];
  const float* uv_W2 = (const float*)d_in[27];
  const float* uv_b2 = (const float*)d_in[28];

  float* ws = (float*)d_ws;
  size_t off = 0;
  float*  S    = ws + off; off += (size_t)NN*64;
  float*  SN   = ws + off; off += (size_t)NN*64;
  float*  V0   = ws + off; off += (size_t)NN*192;
  float*  V1   = ws + off; off += (size_t)NN*192;
  float4* UD   = (float4*)(ws + off); off += (size_t)EE*4;
  float4* UDP  = (float4*)(ws + off); off += (size_t)EE*4;
  float*  GS   = ws + off; off += GG;
  float*  GQ   = ws + off; off += GG;
  float*  MEANV= ws + off; off += GG;
  float*  INVV = ws + off; off += GG;
  int*    CNT  = (int*)(ws + off); off += GG;
  off = (off + 3) & ~(size_t)3;          // 16B-align
  ushort* SH   = (ushort*)(ws + off); off += (size_t)NN*32;
  ushort* SL   = (ushort*)(ws + off); off += (size_t)NN*32;
  ushort* PHIb = (ushort*)(ws + off); off += (size_t)NN*96;
  ushort* V0b  = (ushort*)(ws + off); off += (size_t)NN*96;
  ushort* W1H = (ushort*)(ws + off); off += (size_t)LL*24576/2;
  ushort* W1L = (ushort*)(ws + off); off += (size_t)LL*24576/2;
  ushort* W2H = (ushort*)(ws + off); off += (size_t)LL*8192/2;
  ushort* W2L = (ushort*)(ws + off); off += (size_t)LL*8192/2;
  ushort* W3H = (ushort*)(ws + off); off += (size_t)LL*12288/2;
  ushort* W3L = (ushort*)(ws + off); off += (size_t)LL*12288/2;
  int*    HIST = (int*)(ws + off); off += NN;
  int*    BASE = (int*)(ws + off); off += NN;
  int*    CUR  = (int*)(ws + off); off += NN;
  int*    SRCp = (int*)(ws + off); off += EE;
  int*    DSTp = (int*)(ws + off); off += EE;

  hipMemsetAsync(HIST, 0, NN*sizeof(int), stream);
  hipMemsetAsync(CUR,  0, NN*sizeof(int), stream);
  hipMemsetAsync(V0, 0, (size_t)NN*192*sizeof(float), stream);
  hipMemsetAsync(V0b, 0, (size_t)NN*192*sizeof(ushort), stream);

  k_geom   <<<(EE+255)/256, 256, 0, stream>>>(node_positions, edges, UD);
  k_counts <<<1, 32, 0, stream>>>(gids, CNT);
  k_proj   <<<(NN+255)/256, 256, 0, stream>>>(node_features, proj_W1, proj_b1, proj_W2, proj_b2, S, SH, SL);
  k_prep_w <<<(LL*45056+255)/256, 256, 0, stream>>>(el_W1, el_W2, in_W, W1H, W1L, W2H, W2L, W3H, W3L);
  k_hist   <<<(EE+255)/256, 256, 0, stream>>>(edges, HIST);
  k_scan   <<<1, 256, 0, stream>>>(HIST, BASE);
  k_scatter<<<(EE+255)/256, 256, 0, stream>>>(edges, BASE, CUR, SRCp, DSTp, UD, UDP);

  for(int l=0; l<LL; l++){
    hipMemsetAsync(GS, 0, 2*GG*sizeof(float), stream);
    k_ln_reduce<<<(NN+255)/256, 256, 0, stream>>>(S, gids, GS, GQ);
    k_ln_final <<<1, 64, 0, stream>>>(GS, GQ, CNT, MEANV, INVV);
    k_node_pre <<<(NN+3)/4, 256, 0, stream>>>(S, gids, MEANV, INVV,
                   ln_g + l*64, ln_b + l*64,
                   msg_W1 + l*64*64, msg_b1 + l*64,
                   msg_W2 + l*64*192, msg_b2 + l*192, SN, PHIb);
    hipMemcpyAsync(V1, V0, (size_t)NN*192*sizeof(float), hipMemcpyDeviceToDevice, stream);
    k_edge<<<EE/TE, 256, 0, stream>>>(SH, SL, PHIb, V0b, UDP, SRCp, DSTp,
                   ef_W + l*64, ef_b + l*64,
                   W1H + l*24576, W1L + l*24576, el_b1 + l*128,
                   W2H + l*8192,  W2L + l*8192,  el_b2 + l*64,
                   W3H + l*12288, W3L + l*12288, in_b + l*192,
                   ei_W + l*64, ei_b + l, SN, V1);
    float* sout = (l == LL-1) ? (float*)d_out : S;
    k_node_post<<<(NN+3)/4, 256, 0, stream>>>(SN, V1,
                   up_UV + l*64*128,
                   uv_W1 + l*128*64, uv_b1 + l*64,
                   uv_W2 + l*64*192, uv_b2 + l*192, sout, V0, SH, SL, V0b);
  }
}